// Round 1
// baseline (370.882 us; speedup 1.0000x reference)
//
#include <hip/hip_runtime.h>

typedef unsigned short u16;
typedef unsigned int u32;
typedef __bf16 bf16x8 __attribute__((ext_vector_type(8)));
typedef float f32x4 __attribute__((ext_vector_type(4)));

#define BB 2
#define TT 2048
#define CC 1024
#define HH 16
#define DD 64
#define MR (BB*TT)   // 4096
#define NQ (3*CC)    // 3072

__device__ __forceinline__ u16 f2b(float f) {
    u32 u = __builtin_bit_cast(u32, f);
    u = (u + 0x7fffu + ((u >> 16) & 1u)) >> 16;
    return (u16)u;
}
__device__ __forceinline__ float b2f(u16 b) {
    return __builtin_bit_cast(float, (u32)b << 16);
}

// ---------------- fp32 -> bf16 convert ----------------
__global__ void cvt_f32_bf16(const float* __restrict__ in, u16* __restrict__ out, int n4) {
    int i = blockIdx.x * 256 + threadIdx.x;
    if (i >= n4) return;
    float4 v = reinterpret_cast<const float4*>(in)[i];
    ushort4 o;
    o.x = f2b(v.x); o.y = f2b(v.y); o.z = f2b(v.z); o.w = f2b(v.w);
    reinterpret_cast<ushort4*>(out)[i] = o;
}

// ---------------- GEMM: out[m][n] = sum_k A[m][k]*Bm[n][k] + bias[n] ----------------
// A: M x K bf16 row-major, Bm: N x K bf16 row-major. 128x128 tile, 4 waves (2x2), 64x64/wave.
template<int BF16_OUT>
__global__ __launch_bounds__(256) void gemm_bt(
    const u16* __restrict__ A, const u16* __restrict__ Bm,
    const float* __restrict__ bias, void* __restrict__ outp,
    int M, int N, int K)
{
    __shared__ u16 As[128][40];
    __shared__ u16 Bs[128][40];
    const int tid = threadIdx.x;
    const int lane = tid & 63;
    const int w = tid >> 6;
    const int wr = w >> 1, wc = w & 1;
    const int fr = lane & 15, fq = lane >> 4;
    const int brow = blockIdx.y * 128, bcol = blockIdx.x * 128;
    const int r0 = tid >> 2, c0 = (tid & 3) * 8;

    f32x4 acc[4][4];
    const f32x4 zero = {0.f, 0.f, 0.f, 0.f};
#pragma unroll
    for (int i = 0; i < 4; i++)
#pragma unroll
        for (int j = 0; j < 4; j++) acc[i][j] = zero;

    for (int kt = 0; kt < K; kt += 32) {
#pragma unroll
        for (int hh = 0; hh < 2; ++hh) {
            const int row = r0 + hh * 64;
            const uint4 av = *reinterpret_cast<const uint4*>(&A[(size_t)(brow + row) * K + kt + c0]);
            *reinterpret_cast<uint4*>(&As[row][c0]) = av;
            const uint4 bv = *reinterpret_cast<const uint4*>(&Bm[(size_t)(bcol + row) * K + kt + c0]);
            *reinterpret_cast<uint4*>(&Bs[row][c0]) = bv;
        }
        __syncthreads();
        bf16x8 af[4], bfr[4];
#pragma unroll
        for (int mi = 0; mi < 4; mi++)
            af[mi] = *reinterpret_cast<const bf16x8*>(&As[wr * 64 + mi * 16 + fr][fq * 8]);
#pragma unroll
        for (int nj = 0; nj < 4; nj++)
            bfr[nj] = *reinterpret_cast<const bf16x8*>(&Bs[wc * 64 + nj * 16 + fr][fq * 8]);
#pragma unroll
        for (int mi = 0; mi < 4; mi++)
#pragma unroll
            for (int nj = 0; nj < 4; nj++)
                acc[mi][nj] = __builtin_amdgcn_mfma_f32_16x16x32_bf16(af[mi], bfr[nj], acc[mi][nj], 0, 0, 0);
        __syncthreads();
    }

#pragma unroll
    for (int mi = 0; mi < 4; mi++) {
#pragma unroll
        for (int nj = 0; nj < 4; nj++) {
            const int n = bcol + wc * 64 + nj * 16 + fr;
            const float bn = bias[n];
#pragma unroll
            for (int r = 0; r < 4; r++) {
                const int m = brow + wr * 64 + mi * 16 + fq * 4 + r;
                const float v = acc[mi][nj][r] + bn;
                if (BF16_OUT) reinterpret_cast<u16*>(outp)[(size_t)m * N + n] = f2b(v);
                else          reinterpret_cast<float*>(outp)[(size_t)m * N + n] = v;
            }
        }
    }
}

// ---------------- RoPE + reorder (B,T,3C) -> (B,H,T,D) ----------------
__global__ void rope_reorder(const u16* __restrict__ qkv,
                             u16* __restrict__ Qr, u16* __restrict__ Kr, u16* __restrict__ Vr)
{
    const int idx = blockIdx.x * 256 + threadIdx.x;  // 2^21 total
    const int j = idx & 31;
    const int h = (idx >> 5) & 15;
    const int t = (idx >> 9) & 2047;
    const int b = idx >> 20;
    const size_t mrow = (size_t)(b * TT + t) * NQ;
    const float theta = __expf((float)(2 * j) * (-0.14391157f)); // -ln(1e4)/64
    const float ang = (float)t * theta;
    const float cs = cosf(ang), sn = sinf(ang);
    const int qc = h * DD + 2 * j;
    const float q0 = b2f(qkv[mrow + qc]),          q1 = b2f(qkv[mrow + qc + 1]);
    const float k0 = b2f(qkv[mrow + CC + qc]),     k1 = b2f(qkv[mrow + CC + qc + 1]);
    const size_t obase = ((size_t)(b * HH + h) * TT + t) * DD + 2 * j;
    Qr[obase]     = f2b(q0 * cs - q1 * sn);
    Qr[obase + 1] = f2b(q1 * cs + q0 * sn);
    Kr[obase]     = f2b(k0 * cs - k1 * sn);
    Kr[obase + 1] = f2b(k1 * cs + k0 * sn);
    Vr[obase]     = qkv[mrow + 2 * CC + qc];
    Vr[obase + 1] = qkv[mrow + 2 * CC + qc + 1];
}

// ---------------- causal flash attention ----------------
// grid (T/64, B*H), 256 thr. wave w: 16 q-rows. KV tiles of 32.
__global__ __launch_bounds__(256) void attn_fwd(
    const u16* __restrict__ Q, const u16* __restrict__ Kg, const u16* __restrict__ Vg,
    u16* __restrict__ Y)
{
    __shared__ u16 Ks[32][80];
    __shared__ u16 Vt[64][40];       // transposed: Vt[d][key]
    __shared__ u16 Ps[4][16][48];    // per-wave P staging
    const int tid = threadIdx.x;
    const int lane = tid & 63, w = tid >> 6;
    const int fr = lane & 15, fq = lane >> 4;
    const int bh = blockIdx.y;
    const int b = bh >> 4, h = bh & 15;
    const int q0 = blockIdx.x * 64;
    const int qb = q0 + w * 16;
    const size_t base = (size_t)bh * TT * DD;

    bf16x8 qf[2];
#pragma unroll
    for (int c = 0; c < 2; c++)
        qf[c] = *reinterpret_cast<const bf16x8*>(&Q[base + (size_t)(qb + fr) * DD + c * 32 + fq * 8]);

    const f32x4 zero = {0.f, 0.f, 0.f, 0.f};
    float m_[4], l_[4];
    f32x4 acc[4];
#pragma unroll
    for (int r = 0; r < 4; r++) { m_[r] = -1e30f; l_[r] = 0.f; acc[r] = zero; }

    const int srow = tid >> 3;        // 0..31
    const int scol = (tid & 7) * 8;   // 0..56

    for (int kv0 = 0; kv0 < q0 + 64; kv0 += 32) {
        // stage K row-major, V transposed
        const uint4 kvv = *reinterpret_cast<const uint4*>(&Kg[base + (size_t)(kv0 + srow) * DD + scol]);
        *reinterpret_cast<uint4*>(&Ks[srow][scol]) = kvv;
        const uint4 vvv = *reinterpret_cast<const uint4*>(&Vg[base + (size_t)(kv0 + srow) * DD + scol]);
        const u16* vp = reinterpret_cast<const u16*>(&vvv);
#pragma unroll
        for (int i = 0; i < 8; i++) Vt[scol + i][srow] = vp[i];
        __syncthreads();

        if (kv0 <= qb + 15) {   // wave-uniform; skip fully-masked tiles
            f32x4 s[2];
#pragma unroll
            for (int sub = 0; sub < 2; ++sub) {
                f32x4 a = zero;
#pragma unroll
                for (int c = 0; c < 2; c++) {
                    bf16x8 kb = *reinterpret_cast<const bf16x8*>(&Ks[sub * 16 + fr][c * 32 + fq * 8]);
                    a = __builtin_amdgcn_mfma_f32_16x16x32_bf16(qf[c], kb, a, 0, 0, 0);
                }
                s[sub] = a;
            }
            // scale + causal mask
#pragma unroll
            for (int sub = 0; sub < 2; ++sub)
#pragma unroll
                for (int r = 0; r < 4; r++) {
                    const int qg = qb + fq * 4 + r;
                    const int kg = kv0 + sub * 16 + fr;
                    const float v = s[sub][r] * 0.125f;
                    s[sub][r] = (kg > qg) ? -1e30f : v;
                }
            // row max (16-lane tree), online-softmax update
            float scl[4];
#pragma unroll
            for (int r = 0; r < 4; r++) {
                float tm = fmaxf(s[0][r], s[1][r]);
                tm = fmaxf(tm, __shfl_xor(tm, 1));
                tm = fmaxf(tm, __shfl_xor(tm, 2));
                tm = fmaxf(tm, __shfl_xor(tm, 4));
                tm = fmaxf(tm, __shfl_xor(tm, 8));
                const float mn = fmaxf(m_[r], tm);
                scl[r] = __expf(m_[r] - mn);
                m_[r] = mn;
            }
#pragma unroll
            for (int r = 0; r < 4; r++) {
                float rs = 0.f;
#pragma unroll
                for (int sub = 0; sub < 2; sub++) {
                    const float p = __expf(s[sub][r] - m_[r]);
                    s[sub][r] = p;
                    rs += p;
                }
                rs += __shfl_xor(rs, 1);
                rs += __shfl_xor(rs, 2);
                rs += __shfl_xor(rs, 4);
                rs += __shfl_xor(rs, 8);
                l_[r] = l_[r] * scl[r] + rs;
#pragma unroll
                for (int nj = 0; nj < 4; nj++) acc[nj][r] *= scl[r];
            }
            // P (C-layout) -> LDS -> A-layout
#pragma unroll
            for (int sub = 0; sub < 2; sub++)
#pragma unroll
                for (int r = 0; r < 4; r++)
                    Ps[w][fq * 4 + r][sub * 16 + fr] = f2b(s[sub][r]);
            asm volatile("s_waitcnt lgkmcnt(0)" ::: "memory");
            __builtin_amdgcn_sched_barrier(0);
            bf16x8 pa = *reinterpret_cast<const bf16x8*>(&Ps[w][fr][fq * 8]);
#pragma unroll
            for (int nj = 0; nj < 4; nj++) {
                bf16x8 vb = *reinterpret_cast<const bf16x8*>(&Vt[nj * 16 + fr][fq * 8]);
                acc[nj] = __builtin_amdgcn_mfma_f32_16x16x32_bf16(pa, vb, acc[nj], 0, 0, 0);
            }
        }
        __syncthreads();
    }

    // Y in (B, T, H, D) = (B,T,C) layout for proj GEMM
#pragma unroll
    for (int nj = 0; nj < 4; nj++)
#pragma unroll
        for (int r = 0; r < 4; r++) {
            const int qg = qb + fq * 4 + r;
            const int d = nj * 16 + fr;
            const float v = acc[nj][r] / l_[r];
            Y[(size_t)(b * TT + qg) * CC + h * DD + d] = f2b(v);
        }
}

extern "C" void kernel_launch(void* const* d_in, const int* in_sizes, int n_in,
                              void* d_out, int out_size, void* d_ws, size_t ws_size,
                              hipStream_t stream)
{
    const float* x     = (const float*)d_in[0];
    const float* Wqkv  = (const float*)d_in[1];
    const float* bqkv  = (const float*)d_in[2];
    const float* Wproj = (const float*)d_in[3];
    const float* bproj = (const float*)d_in[4];
    float* out = (float*)d_out;

    u16* ws     = (u16*)d_ws;
    u16* xb     = ws;                               // 4096*1024
    u16* wqkvb  = xb     + (size_t)MR * CC;         // 3072*1024
    u16* wprojb = wqkvb  + (size_t)NQ * CC;         // 1024*1024
    u16* qkv    = wprojb + (size_t)CC * CC;         // 4096*3072
    u16* Qr     = qkv    + (size_t)MR * NQ;         // 2*16*2048*64
    u16* Kr     = Qr     + (size_t)BB * HH * TT * DD;
    u16* Vr     = Kr     + (size_t)BB * HH * TT * DD;
    u16* yb     = Vr     + (size_t)BB * HH * TT * DD; // 4096*1024

    cvt_f32_bf16<<<dim3(MR * CC / 1024), 256, 0, stream>>>(x, xb, MR * CC / 4);
    cvt_f32_bf16<<<dim3(NQ * CC / 1024), 256, 0, stream>>>(Wqkv, wqkvb, NQ * CC / 4);
    cvt_f32_bf16<<<dim3(CC * CC / 1024), 256, 0, stream>>>(Wproj, wprojb, CC * CC / 4);

    gemm_bt<1><<<dim3(NQ / 128, MR / 128), 256, 0, stream>>>(xb, wqkvb, bqkv, qkv, MR, NQ, CC);

    rope_reorder<<<dim3(BB * TT * HH * 32 / 256), 256, 0, stream>>>(qkv, Qr, Kr, Vr);

    attn_fwd<<<dim3(TT / 64, BB * HH), 256, 0, stream>>>(Qr, Kr, Vr, yb);

    gemm_bt<0><<<dim3(CC / 128, MR / 128), 256, 0, stream>>>(yb, wprojb, bproj, out, MR, CC, CC);
}

// Round 2
// 290.735 us; speedup vs baseline: 1.2757x; 1.2757x over previous
//
#include <hip/hip_runtime.h>

typedef unsigned short u16;
typedef unsigned int u32;
typedef __bf16 bf16x8 __attribute__((ext_vector_type(8)));
typedef float f32x4 __attribute__((ext_vector_type(4)));

#define BB 2
#define TT 2048
#define CC 1024
#define HH 16
#define DD 64
#define MR (BB*TT)   // 4096
#define NQ (3*CC)    // 3072

__device__ __forceinline__ u16 f2b(float f) {
    u32 u = __builtin_bit_cast(u32, f);
    u = (u + 0x7fffu + ((u >> 16) & 1u)) >> 16;
    return (u16)u;
}
__device__ __forceinline__ float b2f(u16 b) {
    return __builtin_bit_cast(float, (u32)b << 16);
}

__device__ __forceinline__ void gll16(const void* g, void* l) {
    __builtin_amdgcn_global_load_lds(
        (const __attribute__((address_space(1))) void*)g,
        (__attribute__((address_space(3))) void*)l,
        16, 0, 0);
}

// ---------------- fp32 -> bf16 convert ----------------
__global__ void cvt_f32_bf16(const float* __restrict__ in, u16* __restrict__ out, int n4) {
    int i = blockIdx.x * 256 + threadIdx.x;
    if (i >= n4) return;
    float4 v = reinterpret_cast<const float4*>(in)[i];
    ushort4 o;
    o.x = f2b(v.x); o.y = f2b(v.y); o.z = f2b(v.z); o.w = f2b(v.w);
    reinterpret_cast<ushort4*>(out)[i] = o;
}

// ---------------- GEMM (m97 structure): out[m][n] = sum_k A[m][k]*Bm[n][k] + bias[n] ----
// A: M x K bf16 row-major, Bm: N x K bf16 row-major. 128x128 tile, BK=32,
// linear LDS + global_load_lds width-16, 2 barriers per K-step.
template<int BF16_OUT>
__global__ __launch_bounds__(256) void gemm_bt(
    const u16* __restrict__ A, const u16* __restrict__ Bm,
    const float* __restrict__ bias, void* __restrict__ outp,
    int M, int N, int K)
{
    __shared__ __align__(16) u16 As[128 * 32];
    __shared__ __align__(16) u16 Bs[128 * 32];
    const int tid = threadIdx.x;
    const int lane = tid & 63;
    const int w = tid >> 6;
    const int wr = w >> 1, wc = w & 1;
    const int fr = lane & 15, fq = lane >> 4;
    const int brow = blockIdx.y * 128, bcol = blockIdx.x * 128;
    const int srow = lane >> 2;          // 0..15
    const int scol = (lane & 3) * 8;     // u16 col

    f32x4 acc[4][4];
    const f32x4 zero = {0.f, 0.f, 0.f, 0.f};
#pragma unroll
    for (int i = 0; i < 4; i++)
#pragma unroll
        for (int j = 0; j < 4; j++) acc[i][j] = zero;

    for (int kt = 0; kt < K; kt += 32) {
#pragma unroll
        for (int i = 0; i < 2; i++) {
            const int r = i * 64 + w * 16 + srow;
            gll16(&A[(size_t)(brow + r) * K + kt + scol], &As[(i * 64 + w * 16) * 32]);
            gll16(&Bm[(size_t)(bcol + r) * K + kt + scol], &Bs[(i * 64 + w * 16) * 32]);
        }
        __syncthreads();
        bf16x8 af[4], bfr[4];
#pragma unroll
        for (int mi = 0; mi < 4; mi++)
            af[mi] = *reinterpret_cast<const bf16x8*>(&As[(wr * 64 + mi * 16 + fr) * 32 + fq * 8]);
#pragma unroll
        for (int nj = 0; nj < 4; nj++)
            bfr[nj] = *reinterpret_cast<const bf16x8*>(&Bs[(wc * 64 + nj * 16 + fr) * 32 + fq * 8]);
#pragma unroll
        for (int mi = 0; mi < 4; mi++)
#pragma unroll
            for (int nj = 0; nj < 4; nj++)
                acc[mi][nj] = __builtin_amdgcn_mfma_f32_16x16x32_bf16(af[mi], bfr[nj], acc[mi][nj], 0, 0, 0);
        __syncthreads();
    }

#pragma unroll
    for (int mi = 0; mi < 4; mi++) {
#pragma unroll
        for (int nj = 0; nj < 4; nj++) {
            const int n = bcol + wc * 64 + nj * 16 + fr;
            const float bn = bias[n];
#pragma unroll
            for (int r = 0; r < 4; r++) {
                const int m = brow + wr * 64 + mi * 16 + fq * 4 + r;
                const float v = acc[mi][nj][r] + bn;
                if (BF16_OUT) reinterpret_cast<u16*>(outp)[(size_t)m * N + n] = f2b(v);
                else          reinterpret_cast<float*>(outp)[(size_t)m * N + n] = v;
            }
        }
    }
}

// ---------------- RoPE + reorder Q,K: (B,T,3C) -> (B,H,T,D) ----------------
__global__ void rope_reorder(const u16* __restrict__ qkv,
                             u16* __restrict__ Qr, u16* __restrict__ Kr)
{
    const int idx = blockIdx.x * 256 + threadIdx.x;  // 2^21 total
    const int j = idx & 31;
    const int h = (idx >> 5) & 15;
    const int t = (idx >> 9) & 2047;
    const int b = idx >> 20;
    const size_t mrow = (size_t)(b * TT + t) * NQ;
    const float theta = __expf((float)(2 * j) * (-0.14391157f)); // -ln(1e4)/64
    const float ang = (float)t * theta;
    const float cs = cosf(ang), sn = sinf(ang);
    const int qc = h * DD + 2 * j;
    const float q0 = b2f(qkv[mrow + qc]),          q1 = b2f(qkv[mrow + qc + 1]);
    const float k0 = b2f(qkv[mrow + CC + qc]),     k1 = b2f(qkv[mrow + CC + qc + 1]);
    const size_t obase = ((size_t)(b * HH + h) * TT + t) * DD + 2 * j;
    Qr[obase]     = f2b(q0 * cs - q1 * sn);
    Qr[obase + 1] = f2b(q1 * cs + q0 * sn);
    Kr[obase]     = f2b(k0 * cs - k1 * sn);
    Kr[obase + 1] = f2b(k1 * cs + k0 * sn);
}

// ---------------- V transpose: qkv V-part (B,T,H,D) -> Vt (B,H,D,T) ----------------
// one wave per 64x64 tile; lane = d. Reads coalesced (wave reads one 128B row per instr).
__global__ __launch_bounds__(64) void vtrans(const u16* __restrict__ qkv, u16* __restrict__ Vtg)
{
    const int lane = threadIdx.x;        // d 0..63
    const int t0 = blockIdx.x * 64;
    const int bh = blockIdx.y;
    const int b = bh >> 4, h = bh & 15;
    u32 packed[32];
#pragma unroll
    for (int tt = 0; tt < 64; tt += 2) {
        const u16 a = qkv[(size_t)(b * TT + t0 + tt) * NQ + 2 * CC + h * DD + lane];
        const u16 c = qkv[(size_t)(b * TT + t0 + tt + 1) * NQ + 2 * CC + h * DD + lane];
        packed[tt >> 1] = (u32)a | ((u32)c << 16);
    }
    u32* dst = reinterpret_cast<u32*>(&Vtg[((size_t)bh * DD + lane) * TT + t0]);
#pragma unroll
    for (int i = 0; i < 32; i += 4)
        *reinterpret_cast<uint4*>(&dst[i]) = make_uint4(packed[i], packed[i + 1], packed[i + 2], packed[i + 3]);
}

// ---------------- causal flash attention ----------------
// 1D grid 512: XCD-sliced (4 bh per XCD -> K/V 2MB fits L2), heavy blocks first.
// 4 waves x 32 q-rows = 128 q-rows/block. KV tiles of 64.
__global__ __launch_bounds__(256) void attn_fwd(
    const u16* __restrict__ Q, const u16* __restrict__ Kg, const u16* __restrict__ Vtg,
    u16* __restrict__ Y)
{
    __shared__ __align__(16) u16 Ks[64][72];
    __shared__ __align__(16) u16 Vs[64][72];
    __shared__ __align__(16) u16 Ps[4][32][72];
    const int tid = threadIdx.x;
    const int lane = tid & 63, w = tid >> 6;
    const int fr = lane & 15, fq = lane >> 4;
    // decode: xcd slice + reversed bx (heavy first)
    const int id = blockIdx.x;           // 0..511
    const int xcd = id & 7, slot = id >> 3;
    const int bh = (slot >> 4) * 8 + xcd;
    const int bx = 15 - (slot & 15);
    const int q0 = bx * 128;
    const int b = bh >> 4, h = bh & 15;
    const int qb = q0 + w * 32;
    const size_t base = (size_t)bh * TT * DD;
    const size_t vbase = (size_t)bh * DD * TT;

    bf16x8 qf[2][2];
#pragma unroll
    for (int qs = 0; qs < 2; qs++)
#pragma unroll
        for (int c = 0; c < 2; c++)
            qf[qs][c] = *reinterpret_cast<const bf16x8*>(
                &Q[base + (size_t)(qb + qs * 16 + fr) * DD + c * 32 + fq * 8]);

    const f32x4 zero = {0.f, 0.f, 0.f, 0.f};
    f32x4 acc[2][4];
    float m_[2][4], l_[2][4];
#pragma unroll
    for (int qs = 0; qs < 2; qs++)
#pragma unroll
        for (int r = 0; r < 4; r++) {
            m_[qs][r] = -1e30f; l_[qs][r] = 0.f;
            acc[qs][r & 3] = zero;   // init below properly
        }
#pragma unroll
    for (int qs = 0; qs < 2; qs++)
#pragma unroll
        for (int nj = 0; nj < 4; nj++) acc[qs][nj] = zero;

    const int srow = tid >> 2;       // 0..63
    const int sc = tid & 3;          // 0..3

    const int kv_end = q0 + 128;
    for (int kv0 = 0; kv0 < kv_end; kv0 += 64) {
#pragma unroll
        for (int rr = 0; rr < 2; rr++) {
            const int cu = (rr * 4 + sc) * 8;
            *reinterpret_cast<uint4*>(&Ks[srow][cu]) =
                *reinterpret_cast<const uint4*>(&Kg[base + (size_t)(kv0 + srow) * DD + cu]);
            *reinterpret_cast<uint4*>(&Vs[srow][cu]) =
                *reinterpret_cast<const uint4*>(&Vtg[vbase + (size_t)srow * TT + kv0 + cu]);
        }
        __syncthreads();

        if (kv0 <= qb + 31) {
            f32x4 s[2][4];
#pragma unroll
            for (int qs = 0; qs < 2; qs++)
#pragma unroll
                for (int ks = 0; ks < 4; ks++) {
                    f32x4 a = zero;
#pragma unroll
                    for (int c = 0; c < 2; c++) {
                        bf16x8 kb = *reinterpret_cast<const bf16x8*>(&Ks[ks * 16 + fr][c * 32 + fq * 8]);
                        a = __builtin_amdgcn_mfma_f32_16x16x32_bf16(qf[qs][c], kb, a, 0, 0, 0);
                    }
                    s[qs][ks] = a;
                }
            // scale + causal mask
#pragma unroll
            for (int qs = 0; qs < 2; qs++)
#pragma unroll
                for (int ks = 0; ks < 4; ks++)
#pragma unroll
                    for (int r = 0; r < 4; r++) {
                        const int qg = qb + qs * 16 + fq * 4 + r;
                        const int kg = kv0 + ks * 16 + fr;
                        const float v = s[qs][ks][r] * 0.125f;
                        s[qs][ks][r] = (kg > qg) ? -1e30f : v;
                    }
            // online softmax per (qs, r)
#pragma unroll
            for (int qs = 0; qs < 2; qs++)
#pragma unroll
                for (int r = 0; r < 4; r++) {
                    float tm = fmaxf(fmaxf(s[qs][0][r], s[qs][1][r]), fmaxf(s[qs][2][r], s[qs][3][r]));
                    tm = fmaxf(tm, __shfl_xor(tm, 1));
                    tm = fmaxf(tm, __shfl_xor(tm, 2));
                    tm = fmaxf(tm, __shfl_xor(tm, 4));
                    tm = fmaxf(tm, __shfl_xor(tm, 8));
                    const float mn = fmaxf(m_[qs][r], tm);
                    const float scl = __expf(m_[qs][r] - mn);
                    m_[qs][r] = mn;
                    float rs = 0.f;
#pragma unroll
                    for (int ks = 0; ks < 4; ks++) {
                        const float p = __expf(s[qs][ks][r] - mn);
                        s[qs][ks][r] = p;
                        rs += p;
                    }
                    rs += __shfl_xor(rs, 1);
                    rs += __shfl_xor(rs, 2);
                    rs += __shfl_xor(rs, 4);
                    rs += __shfl_xor(rs, 8);
                    l_[qs][r] = l_[qs][r] * scl + rs;
#pragma unroll
                    for (int nj = 0; nj < 4; nj++) acc[qs][nj][r] *= scl;
                }
            // P (C-layout) -> per-wave LDS
#pragma unroll
            for (int qs = 0; qs < 2; qs++)
#pragma unroll
                for (int ks = 0; ks < 4; ks++)
#pragma unroll
                    for (int r = 0; r < 4; r++)
                        Ps[w][qs * 16 + fq * 4 + r][ks * 16 + fr] = f2b(s[qs][ks][r]);
            asm volatile("s_waitcnt lgkmcnt(0)" ::: "memory");
            __builtin_amdgcn_sched_barrier(0);
            // PV
#pragma unroll
            for (int qs = 0; qs < 2; qs++) {
                bf16x8 pa0 = *reinterpret_cast<const bf16x8*>(&Ps[w][qs * 16 + fr][fq * 8]);
                bf16x8 pa1 = *reinterpret_cast<const bf16x8*>(&Ps[w][qs * 16 + fr][32 + fq * 8]);
#pragma unroll
                for (int nj = 0; nj < 4; nj++) {
                    bf16x8 vb0 = *reinterpret_cast<const bf16x8*>(&Vs[nj * 16 + fr][fq * 8]);
                    bf16x8 vb1 = *reinterpret_cast<const bf16x8*>(&Vs[nj * 16 + fr][32 + fq * 8]);
                    acc[qs][nj] = __builtin_amdgcn_mfma_f32_16x16x32_bf16(pa0, vb0, acc[qs][nj], 0, 0, 0);
                    acc[qs][nj] = __builtin_amdgcn_mfma_f32_16x16x32_bf16(pa1, vb1, acc[qs][nj], 0, 0, 0);
                }
            }
        }
        __syncthreads();
    }

    // Y in (B, T, H, D) = (B,T,C) layout for proj GEMM
#pragma unroll
    for (int qs = 0; qs < 2; qs++)
#pragma unroll
        for (int nj = 0; nj < 4; nj++)
#pragma unroll
            for (int r = 0; r < 4; r++) {
                const int qg = qb + qs * 16 + fq * 4 + r;
                const int d = nj * 16 + fr;
                const float v = acc[qs][nj][r] / l_[qs][r];
                Y[(size_t)(b * TT + qg) * CC + h * DD + d] = f2b(v);
            }
}

extern "C" void kernel_launch(void* const* d_in, const int* in_sizes, int n_in,
                              void* d_out, int out_size, void* d_ws, size_t ws_size,
                              hipStream_t stream)
{
    const float* x     = (const float*)d_in[0];
    const float* Wqkv  = (const float*)d_in[1];
    const float* bqkv  = (const float*)d_in[2];
    const float* Wproj = (const float*)d_in[3];
    const float* bproj = (const float*)d_in[4];
    float* out = (float*)d_out;

    u16* ws     = (u16*)d_ws;
    u16* xb     = ws;                               // 4096*1024
    u16* wqkvb  = xb     + (size_t)MR * CC;         // 3072*1024
    u16* wprojb = wqkvb  + (size_t)NQ * CC;         // 1024*1024
    u16* qkv    = wprojb + (size_t)CC * CC;         // 4096*3072
    u16* Qr     = qkv    + (size_t)MR * NQ;         // 2*16*2048*64
    u16* Kr     = Qr     + (size_t)BB * HH * TT * DD;
    u16* Vtg    = Kr     + (size_t)BB * HH * TT * DD;  // (B,H,D,T)
    u16* yb     = Vtg    + (size_t)BB * HH * TT * DD;  // 4096*1024

    cvt_f32_bf16<<<dim3(MR * CC / 1024), 256, 0, stream>>>(x, xb, MR * CC / 4);
    cvt_f32_bf16<<<dim3(NQ * CC / 1024), 256, 0, stream>>>(Wqkv, wqkvb, NQ * CC / 4);
    cvt_f32_bf16<<<dim3(CC * CC / 1024), 256, 0, stream>>>(Wproj, wprojb, CC * CC / 4);

    gemm_bt<1><<<dim3(NQ / 128, MR / 128), 256, 0, stream>>>(xb, wqkvb, bqkv, qkv, MR, NQ, CC);

    rope_reorder<<<dim3(BB * TT * HH * 32 / 256), 256, 0, stream>>>(qkv, Qr, Kr);
    vtrans<<<dim3(TT / 64, BB * HH), 64, 0, stream>>>(qkv, Vtg);

    attn_fwd<<<dim3(512), 256, 0, stream>>>(Qr, Kr, Vtg, yb);

    gemm_bt<0><<<dim3(CC / 128, MR / 128), 256, 0, stream>>>(yb, wprojb, bproj, out, MR, CC, CC);
}

// Round 3
// 228.666 us; speedup vs baseline: 1.6219x; 1.2714x over previous
//
#include <hip/hip_runtime.h>

typedef unsigned short u16;
typedef unsigned int u32;
typedef __bf16 bf16x8 __attribute__((ext_vector_type(8)));
typedef float f32x4 __attribute__((ext_vector_type(4)));
typedef float f32x16 __attribute__((ext_vector_type(16)));

#define BB 2
#define TT 2048
#define CC 1024
#define HH 16
#define DD 64
#define MR (BB*TT)   // 4096
#define NQ (3*CC)    // 3072

__device__ __forceinline__ u16 f2b(float f) {
    u32 u = __builtin_bit_cast(u32, f);
    u = (u + 0x7fffu + ((u >> 16) & 1u)) >> 16;
    return (u16)u;
}
__device__ __forceinline__ float b2f(u16 b) {
    return __builtin_bit_cast(float, (u32)b << 16);
}
__device__ __forceinline__ u32 pkbf(float a, float b) {
    ushort2 t; t.x = f2b(a); t.y = f2b(b);
    return __builtin_bit_cast(u32, t);
}

__device__ __forceinline__ void gll16(const void* g, void* l) {
    __builtin_amdgcn_global_load_lds(
        (const __attribute__((address_space(1))) void*)g,
        (__attribute__((address_space(3))) void*)l,
        16, 0, 0);
}

// ---------------- fused fp32 -> bf16 convert (x, Wqkv, Wproj) ----------------
__global__ void cvt_all(const float* __restrict__ x, const float* __restrict__ wqkv,
                        const float* __restrict__ wproj,
                        u16* __restrict__ xb, u16* __restrict__ wqkvb, u16* __restrict__ wprojb)
{
    const int n0 = MR * CC / 4, n1 = NQ * CC / 4, n2 = CC * CC / 4;
    int i = blockIdx.x * 256 + threadIdx.x;
    const float* src; u16* dst; int off;
    if (i < n0)           { src = x;     dst = xb;     off = i; }
    else if (i < n0 + n1) { src = wqkv;  dst = wqkvb;  off = i - n0; }
    else if (i < n0 + n1 + n2) { src = wproj; dst = wprojb; off = i - n0 - n1; }
    else return;
    float4 v = reinterpret_cast<const float4*>(src)[off];
    ushort4 o;
    o.x = f2b(v.x); o.y = f2b(v.y); o.z = f2b(v.z); o.w = f2b(v.w);
    reinterpret_cast<ushort4*>(dst)[off] = o;
}

// ---------------- GEMM (m97 structure) ----------------
template<int BF16_OUT>
__global__ __launch_bounds__(256) void gemm_bt(
    const u16* __restrict__ A, const u16* __restrict__ Bm,
    const float* __restrict__ bias, void* __restrict__ outp,
    int M, int N, int K)
{
    __shared__ __align__(16) u16 As[128 * 32];
    __shared__ __align__(16) u16 Bs[128 * 32];
    const int tid = threadIdx.x;
    const int lane = tid & 63;
    const int w = tid >> 6;
    const int wr = w >> 1, wc = w & 1;
    const int fr = lane & 15, fq = lane >> 4;
    const int brow = blockIdx.y * 128, bcol = blockIdx.x * 128;
    const int srow = lane >> 2;
    const int scol = (lane & 3) * 8;

    f32x4 acc[4][4];
    const f32x4 zero = {0.f, 0.f, 0.f, 0.f};
#pragma unroll
    for (int i = 0; i < 4; i++)
#pragma unroll
        for (int j = 0; j < 4; j++) acc[i][j] = zero;

    for (int kt = 0; kt < K; kt += 32) {
#pragma unroll
        for (int i = 0; i < 2; i++) {
            const int r = i * 64 + w * 16 + srow;
            gll16(&A[(size_t)(brow + r) * K + kt + scol], &As[(i * 64 + w * 16) * 32]);
            gll16(&Bm[(size_t)(bcol + r) * K + kt + scol], &Bs[(i * 64 + w * 16) * 32]);
        }
        __syncthreads();
        bf16x8 af[4], bfr[4];
#pragma unroll
        for (int mi = 0; mi < 4; mi++)
            af[mi] = *reinterpret_cast<const bf16x8*>(&As[(wr * 64 + mi * 16 + fr) * 32 + fq * 8]);
#pragma unroll
        for (int nj = 0; nj < 4; nj++)
            bfr[nj] = *reinterpret_cast<const bf16x8*>(&Bs[(wc * 64 + nj * 16 + fr) * 32 + fq * 8]);
#pragma unroll
        for (int mi = 0; mi < 4; mi++)
#pragma unroll
            for (int nj = 0; nj < 4; nj++)
                acc[mi][nj] = __builtin_amdgcn_mfma_f32_16x16x32_bf16(af[mi], bfr[nj], acc[mi][nj], 0, 0, 0);
        __syncthreads();
    }

#pragma unroll
    for (int mi = 0; mi < 4; mi++) {
#pragma unroll
        for (int nj = 0; nj < 4; nj++) {
            const int n = bcol + wc * 64 + nj * 16 + fr;
            const float bn = bias[n];
#pragma unroll
            for (int r = 0; r < 4; r++) {
                const int m = brow + wr * 64 + mi * 16 + fq * 4 + r;
                const float v = acc[mi][nj][r] + bn;
                if (BF16_OUT) reinterpret_cast<u16*>(outp)[(size_t)m * N + n] = f2b(v);
                else          reinterpret_cast<float*>(outp)[(size_t)m * N + n] = v;
            }
        }
    }
}

// ---------------- RoPE + reorder Q,K: (B,T,3C) -> (B,H,T,D) ----------------
__global__ void rope_reorder(const u16* __restrict__ qkv,
                             u16* __restrict__ Qr, u16* __restrict__ Kr)
{
    const int idx = blockIdx.x * 256 + threadIdx.x;
    const int j = idx & 31;
    const int h = (idx >> 5) & 15;
    const int t = (idx >> 9) & 2047;
    const int b = idx >> 20;
    const size_t mrow = (size_t)(b * TT + t) * NQ;
    const float theta = __expf((float)(2 * j) * (-0.14391157f));
    const float ang = (float)t * theta;
    const float cs = cosf(ang), sn = sinf(ang);
    const int qc = h * DD + 2 * j;
    const float q0 = b2f(qkv[mrow + qc]),          q1 = b2f(qkv[mrow + qc + 1]);
    const float k0 = b2f(qkv[mrow + CC + qc]),     k1 = b2f(qkv[mrow + CC + qc + 1]);
    const size_t obase = ((size_t)(b * HH + h) * TT + t) * DD + 2 * j;
    Qr[obase]     = f2b(q0 * cs - q1 * sn);
    Qr[obase + 1] = f2b(q1 * cs + q0 * sn);
    Kr[obase]     = f2b(k0 * cs - k1 * sn);
    Kr[obase + 1] = f2b(k1 * cs + k0 * sn);
}

// ---------------- V transpose: qkv V-part (B,T,H,D) -> Vt (B,H,D,T) ----------------
__global__ __launch_bounds__(64) void vtrans(const u16* __restrict__ qkv, u16* __restrict__ Vtg)
{
    const int lane = threadIdx.x;
    const int t0 = blockIdx.x * 64;
    const int bh = blockIdx.y;
    const int b = bh >> 4, h = bh & 15;
    u32 packed[32];
#pragma unroll
    for (int tt = 0; tt < 64; tt += 2) {
        const u16 a = qkv[(size_t)(b * TT + t0 + tt) * NQ + 2 * CC + h * DD + lane];
        const u16 c = qkv[(size_t)(b * TT + t0 + tt + 1) * NQ + 2 * CC + h * DD + lane];
        packed[tt >> 1] = (u32)a | ((u32)c << 16);
    }
    u32* dst = reinterpret_cast<u32*>(&Vtg[((size_t)bh * DD + lane) * TT + t0]);
#pragma unroll
    for (int i = 0; i < 32; i += 4)
        *reinterpret_cast<uint4*>(&dst[i]) = make_uint4(packed[i], packed[i + 1], packed[i + 2], packed[i + 3]);
}

// ---------------- causal flash attention, 32x32 swapped-operand form ----------------
// grid 512. id&7 = XCD; within XCD, slot l and l+32 land on the same CU and
// carry bx summing to 15 (constant work), same bh (shared K/V in L2).
// 4 waves x 32 q-rows = 128 q-rows/block, KV tiles of 64.
__global__ __launch_bounds__(256) void attn_fwd(
    const u16* __restrict__ Q, const u16* __restrict__ Kg, const u16* __restrict__ Vtg,
    u16* __restrict__ Y)
{
    __shared__ __align__(16) u16 smem[64 * 72 * 2];   // Ks | Vs ; reused for O-transpose
    u16* Ks = smem;
    u16* Vs = smem + 64 * 72;

    const int tid = threadIdx.x;
    const int lane = tid & 63, w = tid >> 6;
    const int ql = lane & 31;       // q-row within wave tile (also d-row for PV A-frag)
    const int hB = lane >> 5;       // frag half
    const int id = blockIdx.x;
    const int xcd = id & 7, l = id >> 3;
    const int bh = (l & 3) * 8 + xcd;
    const int bx = (l < 32) ? (15 - (l >> 2)) : ((l - 32) >> 2);
    const int q0 = bx * 128;
    const int b = bh >> 4, hh = bh & 15;
    const int qb = q0 + w * 32;
    const int qg = qb + ql;
    const size_t base = (size_t)bh * TT * DD;
    const size_t vbase = (size_t)bh * DD * TT;

    // Q fragments (B-operand): lane(ql,hB) holds Q[qg][ds*16 + hB*8 + j]
    bf16x8 qf[4];
#pragma unroll
    for (int ds = 0; ds < 4; ds++)
        qf[ds] = *reinterpret_cast<const bf16x8*>(&Q[base + (size_t)qg * DD + ds * 16 + hB * 8]);

    f32x16 acc[2];
#pragma unroll
    for (int dh = 0; dh < 2; dh++)
#pragma unroll
        for (int r = 0; r < 16; r++) acc[dh][r] = 0.f;
    float m_ = -1e30f, l_ = 0.f;

    const int srow = tid >> 2;       // 0..63
    const int sc = tid & 3;          // 0..3

    const int kv_end = q0 + 128;
    for (int kv0 = 0; kv0 < kv_end; kv0 += 64) {
#pragma unroll
        for (int rr = 0; rr < 2; rr++) {
            const int cu = (rr * 4 + sc) * 8;
            *reinterpret_cast<uint4*>(&Ks[srow * 72 + cu]) =
                *reinterpret_cast<const uint4*>(&Kg[base + (size_t)(kv0 + srow) * DD + cu]);
            *reinterpret_cast<uint4*>(&Vs[srow * 72 + cu]) =
                *reinterpret_cast<const uint4*>(&Vtg[vbase + (size_t)srow * TT + kv0 + cu]);
        }
        __syncthreads();

        if (kv0 <= qb + 31) {
            // QK^T swapped: sa[st] reg r holds S[q=qg][k = kv0+st*32+(r&3)+8*(r>>2)+4*hB]
            f32x16 sa[2];
#pragma unroll
            for (int st = 0; st < 2; st++)
#pragma unroll
                for (int r = 0; r < 16; r++) sa[st][r] = 0.f;
            __builtin_amdgcn_s_setprio(1);
#pragma unroll
            for (int st = 0; st < 2; st++)
#pragma unroll
                for (int ds = 0; ds < 4; ds++) {
                    bf16x8 kf = *reinterpret_cast<const bf16x8*>(
                        &Ks[(st * 32 + ql) * 72 + ds * 16 + hB * 8]);
                    sa[st] = __builtin_amdgcn_mfma_f32_32x32x16_bf16(kf, qf[ds], sa[st], 0, 0, 0);
                }
            __builtin_amdgcn_s_setprio(0);
            // scale + causal mask
#pragma unroll
            for (int st = 0; st < 2; st++) {
                const int kb0 = kv0 + st * 32 + 4 * hB;
#pragma unroll
                for (int r = 0; r < 16; r++) {
                    const int kg = kb0 + (r & 3) + 8 * (r >> 2);
                    const float v = sa[st][r] * 0.125f;
                    sa[st][r] = (kg > qg) ? -1e30f : v;
                }
            }
            // row max: 31 in-lane + 1 cross-half
            float tm = sa[0][0];
#pragma unroll
            for (int r = 1; r < 16; r++) tm = fmaxf(tm, sa[0][r]);
#pragma unroll
            for (int r = 0; r < 16; r++) tm = fmaxf(tm, sa[1][r]);
            tm = fmaxf(tm, __shfl_xor(tm, 32));
            const float mn = fmaxf(m_, tm);
            const float scl = __expf(m_ - mn);
            m_ = mn;
            // exp + row sum
            float rs = 0.f;
#pragma unroll
            for (int st = 0; st < 2; st++)
#pragma unroll
                for (int r = 0; r < 16; r++) {
                    const float p = __expf(sa[st][r] - mn);
                    sa[st][r] = p;
                    rs += p;
                }
            rs += __shfl_xor(rs, 32);
            l_ = l_ * scl + rs;
#pragma unroll
            for (int dh = 0; dh < 2; dh++)
#pragma unroll
                for (int r = 0; r < 16; r++) acc[dh][r] *= scl;
            // pack P to bf16 word-pairs
            u32 pk[2][8];
#pragma unroll
            for (int st = 0; st < 2; st++)
#pragma unroll
                for (int wd = 0; wd < 8; wd++)
                    pk[st][wd] = pkbf(sa[st][2 * wd], sa[st][2 * wd + 1]);
            // PV: per 16-k chunk c, build P B-frag via 2 permlane32_swap
            __builtin_amdgcn_s_setprio(1);
#pragma unroll
            for (int c = 0; c < 4; c++) {
                u32 a0 = pk[c >> 1][4 * (c & 1) + 0];
                u32 a1 = pk[c >> 1][4 * (c & 1) + 1];
                u32 a2 = pk[c >> 1][4 * (c & 1) + 2];
                u32 a3 = pk[c >> 1][4 * (c & 1) + 3];
                asm volatile("v_permlane32_swap_b32 %0, %1" : "+v"(a0), "+v"(a2));
                asm volatile("v_permlane32_swap_b32 %0, %1" : "+v"(a1), "+v"(a3));
                uint4 tw = make_uint4(a0, a1, a2, a3);
                bf16x8 pb = __builtin_bit_cast(bf16x8, tw);
#pragma unroll
                for (int dh = 0; dh < 2; dh++) {
                    bf16x8 vf = *reinterpret_cast<const bf16x8*>(
                        &Vs[(dh * 32 + ql) * 72 + c * 16 + hB * 8]);
                    acc[dh] = __builtin_amdgcn_mfma_f32_32x32x16_bf16(vf, pb, acc[dh], 0, 0, 0);
                }
            }
            __builtin_amdgcn_s_setprio(0);
        }
        __syncthreads();
    }

    // epilogue: O/l -> per-wave LDS transpose -> coalesced Y write
    const float linv = 1.0f / l_;
    u16* sw = smem + w * (32 * 72);
#pragma unroll
    for (int dh = 0; dh < 2; dh++)
#pragma unroll
        for (int rp = 0; rp < 16; rp += 2) {
            const int d = (rp & 3) + 8 * (rp >> 2) + 4 * hB + 32 * dh;
            *reinterpret_cast<u32*>(&sw[ql * 72 + d]) =
                pkbf(acc[dh][rp] * linv, acc[dh][rp + 1] * linv);
        }
    const int orow = lane >> 1, ocol = (lane & 1) * 32;
    const size_t ybase = (size_t)(b * TT + qb + orow) * CC + hh * DD + ocol;
#pragma unroll
    for (int i = 0; i < 4; i++) {
        uint4 ov = *reinterpret_cast<const uint4*>(&sw[orow * 72 + ocol + i * 8]);
        *reinterpret_cast<uint4*>(&Y[ybase + i * 8]) = ov;
    }
}

extern "C" void kernel_launch(void* const* d_in, const int* in_sizes, int n_in,
                              void* d_out, int out_size, void* d_ws, size_t ws_size,
                              hipStream_t stream)
{
    const float* x     = (const float*)d_in[0];
    const float* Wqkv  = (const float*)d_in[1];
    const float* bqkv  = (const float*)d_in[2];
    const float* Wproj = (const float*)d_in[3];
    const float* bproj = (const float*)d_in[4];
    float* out = (float*)d_out;

    u16* ws     = (u16*)d_ws;
    u16* xb     = ws;
    u16* wqkvb  = xb     + (size_t)MR * CC;
    u16* wprojb = wqkvb  + (size_t)NQ * CC;
    u16* qkv    = wprojb + (size_t)CC * CC;
    u16* Qr     = qkv    + (size_t)MR * NQ;
    u16* Kr     = Qr     + (size_t)BB * HH * TT * DD;
    u16* Vtg    = Kr     + (size_t)BB * HH * TT * DD;
    u16* yb     = Vtg    + (size_t)BB * HH * TT * DD;

    cvt_all<<<dim3(8192), 256, 0, stream>>>(x, Wqkv, Wproj, xb, wqkvb, wprojb);

    gemm_bt<1><<<dim3(NQ / 128, MR / 128), 256, 0, stream>>>(xb, wqkvb, bqkv, qkv, MR, NQ, CC);

    rope_reorder<<<dim3(BB * TT * HH * 32 / 256), 256, 0, stream>>>(qkv, Qr, Kr);
    vtrans<<<dim3(TT / 64, BB * HH), 64, 0, stream>>>(qkv, Vtg);

    attn_fwd<<<dim3(512), 256, 0, stream>>>(Qr, Kr, Vtg, yb);

    gemm_bt<0><<<dim3(CC / 128, MR / 128), 256, 0, stream>>>(yb, wprojb, bproj, out, MR, CC, CC);
}

// Round 4
// 217.696 us; speedup vs baseline: 1.7037x; 1.0504x over previous
//
#include <hip/hip_runtime.h>

typedef unsigned short u16;
typedef unsigned int u32;
typedef __bf16 bf16x8 __attribute__((ext_vector_type(8)));
typedef float f32x4 __attribute__((ext_vector_type(4)));
typedef float f32x16 __attribute__((ext_vector_type(16)));

#define BB 2
#define TT 2048
#define CC 1024
#define HH 16
#define DD 64
#define MR (BB*TT)   // 4096
#define NQ (3*CC)    // 3072
#define SCQ 0.18033688f   // 0.125 * log2(e), folded into Q at rope time

__device__ __forceinline__ u16 f2b(float f) {
    u32 u = __builtin_bit_cast(u32, f);
    u = (u + 0x7fffu + ((u >> 16) & 1u)) >> 16;
    return (u16)u;
}
__device__ __forceinline__ float b2f(u16 b) {
    return __builtin_bit_cast(float, (u32)b << 16);
}
__device__ __forceinline__ u32 pkbf(float a, float b) {
    ushort2 t; t.x = f2b(a); t.y = f2b(b);
    return __builtin_bit_cast(u32, t);
}

__device__ __forceinline__ void gll16(const void* g, void* l) {
    __builtin_amdgcn_global_load_lds(
        (const __attribute__((address_space(1))) void*)g,
        (__attribute__((address_space(3))) void*)l,
        16, 0, 0);
}

// ---------------- fused fp32 -> bf16 convert (x, Wqkv, Wproj) + counter zero ----------------
__global__ void cvt_all(const float* __restrict__ x, const float* __restrict__ wqkv,
                        const float* __restrict__ wproj,
                        u16* __restrict__ xb, u16* __restrict__ wqkvb, u16* __restrict__ wprojb,
                        u32* __restrict__ ctr)
{
    if (blockIdx.x == 0 && threadIdx.x == 0) *ctr = 0;
    const int n0 = MR * CC / 4, n1 = NQ * CC / 4, n2 = CC * CC / 4;
    int i = blockIdx.x * 256 + threadIdx.x;
    const float* src; u16* dst; int off;
    if (i < n0)           { src = x;     dst = xb;     off = i; }
    else if (i < n0 + n1) { src = wqkv;  dst = wqkvb;  off = i - n0; }
    else if (i < n0 + n1 + n2) { src = wproj; dst = wprojb; off = i - n0 - n1; }
    else return;
    float4 v = reinterpret_cast<const float4*>(src)[off];
    ushort4 o;
    o.x = f2b(v.x); o.y = f2b(v.y); o.z = f2b(v.z); o.w = f2b(v.w);
    reinterpret_cast<ushort4*>(dst)[off] = o;
}

// ---------------- GEMM (m97 structure) ----------------
template<int BF16_OUT>
__global__ __launch_bounds__(256) void gemm_bt(
    const u16* __restrict__ A, const u16* __restrict__ Bm,
    const float* __restrict__ bias, void* __restrict__ outp,
    int M, int N, int K)
{
    __shared__ __align__(16) u16 As[128 * 32];
    __shared__ __align__(16) u16 Bs[128 * 32];
    const int tid = threadIdx.x;
    const int lane = tid & 63;
    const int w = tid >> 6;
    const int wr = w >> 1, wc = w & 1;
    const int fr = lane & 15, fq = lane >> 4;
    const int brow = blockIdx.y * 128, bcol = blockIdx.x * 128;
    const int srow = lane >> 2;
    const int scol = (lane & 3) * 8;

    f32x4 acc[4][4];
    const f32x4 zero = {0.f, 0.f, 0.f, 0.f};
#pragma unroll
    for (int i = 0; i < 4; i++)
#pragma unroll
        for (int j = 0; j < 4; j++) acc[i][j] = zero;

    for (int kt = 0; kt < K; kt += 32) {
#pragma unroll
        for (int i = 0; i < 2; i++) {
            const int r = i * 64 + w * 16 + srow;
            gll16(&A[(size_t)(brow + r) * K + kt + scol], &As[(i * 64 + w * 16) * 32]);
            gll16(&Bm[(size_t)(bcol + r) * K + kt + scol], &Bs[(i * 64 + w * 16) * 32]);
        }
        __syncthreads();
        bf16x8 af[4], bfr[4];
#pragma unroll
        for (int mi = 0; mi < 4; mi++)
            af[mi] = *reinterpret_cast<const bf16x8*>(&As[(wr * 64 + mi * 16 + fr) * 32 + fq * 8]);
#pragma unroll
        for (int nj = 0; nj < 4; nj++)
            bfr[nj] = *reinterpret_cast<const bf16x8*>(&Bs[(wc * 64 + nj * 16 + fr) * 32 + fq * 8]);
#pragma unroll
        for (int mi = 0; mi < 4; mi++)
#pragma unroll
            for (int nj = 0; nj < 4; nj++)
                acc[mi][nj] = __builtin_amdgcn_mfma_f32_16x16x32_bf16(af[mi], bfr[nj], acc[mi][nj], 0, 0, 0);
        __syncthreads();
    }

#pragma unroll
    for (int mi = 0; mi < 4; mi++) {
#pragma unroll
        for (int nj = 0; nj < 4; nj++) {
            const int n = bcol + wc * 64 + nj * 16 + fr;
            const float bn = bias[n];
#pragma unroll
            for (int r = 0; r < 4; r++) {
                const int m = brow + wr * 64 + mi * 16 + fq * 4 + r;
                const float v = acc[mi][nj][r] + bn;
                if (BF16_OUT) reinterpret_cast<u16*>(outp)[(size_t)m * N + n] = f2b(v);
                else          reinterpret_cast<float*>(outp)[(size_t)m * N + n] = v;
            }
        }
    }
}

// ---------------- RoPE + reorder Q,K: (B,T,3C) -> (B,H,T,D); Q pre-scaled ----------------
__global__ void rope_reorder(const u16* __restrict__ qkv,
                             u16* __restrict__ Qr, u16* __restrict__ Kr)
{
    const int idx = blockIdx.x * 256 + threadIdx.x;
    const int j = idx & 31;
    const int h = (idx >> 5) & 15;
    const int t = (idx >> 9) & 2047;
    const int b = idx >> 20;
    const size_t mrow = (size_t)(b * TT + t) * NQ;
    const float theta = __expf((float)(2 * j) * (-0.14391157f));
    const float ang = (float)t * theta;
    const float cs = cosf(ang), sn = sinf(ang);
    const int qc = h * DD + 2 * j;
    const float q0 = b2f(qkv[mrow + qc]),          q1 = b2f(qkv[mrow + qc + 1]);
    const float k0 = b2f(qkv[mrow + CC + qc]),     k1 = b2f(qkv[mrow + CC + qc + 1]);
    const size_t obase = ((size_t)(b * HH + h) * TT + t) * DD + 2 * j;
    Qr[obase]     = f2b((q0 * cs - q1 * sn) * SCQ);
    Qr[obase + 1] = f2b((q1 * cs + q0 * sn) * SCQ);
    Kr[obase]     = f2b(k0 * cs - k1 * sn);
    Kr[obase + 1] = f2b(k1 * cs + k0 * sn);
}

// ---------------- V transpose: qkv V-part (B,T,H,D) -> Vt (B,H,D,T) ----------------
__global__ __launch_bounds__(64) void vtrans(const u16* __restrict__ qkv, u16* __restrict__ Vtg)
{
    const int lane = threadIdx.x;
    const int t0 = blockIdx.x * 64;
    const int bh = blockIdx.y;
    const int b = bh >> 4, h = bh & 15;
    u32 packed[32];
#pragma unroll
    for (int tt = 0; tt < 64; tt += 2) {
        const u16 a = qkv[(size_t)(b * TT + t0 + tt) * NQ + 2 * CC + h * DD + lane];
        const u16 c = qkv[(size_t)(b * TT + t0 + tt + 1) * NQ + 2 * CC + h * DD + lane];
        packed[tt >> 1] = (u32)a | ((u32)c << 16);
    }
    u32* dst = reinterpret_cast<u32*>(&Vtg[((size_t)bh * DD + lane) * TT + t0]);
#pragma unroll
    for (int i = 0; i < 32; i += 4)
        *reinterpret_cast<uint4*>(&dst[i]) = make_uint4(packed[i], packed[i + 1], packed[i + 2], packed[i + 3]);
}

// ---------------- causal flash attention: persistent + queue + KV-split ----------------
// 256 blocks x 512 thr (8 waves). Item = (bh, 128-q-rows), 512 items heavy-first.
// Wave-groups g=0/1 scan even/odd 64-key tiles; merge (m,l,acc) via LDS per item.
__global__ __launch_bounds__(512) void attn_fwd(
    const u16* __restrict__ Q, const u16* __restrict__ Kg, const u16* __restrict__ Vtg,
    u16* __restrict__ Y, u32* __restrict__ ctr)
{
    __shared__ __align__(16) u16 smem[4 * 64 * 72];   // Ks0|Vs0|Ks1|Vs1 / fmerge / O-transpose
    __shared__ int cur;
    const int tid = threadIdx.x;
    const int lane = tid & 63;
    const int ql = lane & 31;
    const int hB = lane >> 5;
    const int wq = (tid >> 6) & 3;
    const int g  = tid >> 8;
    const int srow = (tid & 255) >> 2;   // 0..63 staging row
    const int sc   = tid & 3;            // 16B chunk
    u16* KsG = smem + (g * 2 + 0) * 4608;
    u16* VsG = smem + (g * 2 + 1) * 4608;
    float* fm = reinterpret_cast<float*>(smem);

    while (true) {
        if (tid == 0) cur = atomicAdd(ctr, 1);
        __syncthreads();
        const int it = cur;
        __syncthreads();
        if (it >= 512) break;

        const int bx = 15 - (it >> 5);
        const int bh = it & 31;
        const int q0 = bx << 7;
        const int halfL = bx + 1;
        const int b = bh >> 4, hh = bh & 15;
        const int qb = q0 + wq * 32;
        const int qg = qb + ql;
        const size_t base  = (size_t)bh * TT * DD;
        const size_t vbase = (size_t)bh * DD * TT;

        bf16x8 qf[4];
#pragma unroll
        for (int ds = 0; ds < 4; ds++)
            qf[ds] = *reinterpret_cast<const bf16x8*>(&Q[base + (size_t)qg * DD + ds * 16 + hB * 8]);

        f32x16 acc[2];
#pragma unroll
        for (int dh = 0; dh < 2; dh++)
#pragma unroll
            for (int r = 0; r < 16; r++) acc[dh][r] = 0.f;
        float m_ = -1e30f, l_ = 0.f;

        int kv0 = 64 * g;
        // prologue prefetch
        uint4 kr0, kr1, vr0, vr1;
        {
            const size_t kro = base + (size_t)(kv0 + srow) * DD;
            kr0 = *reinterpret_cast<const uint4*>(&Kg[kro + sc * 8]);
            kr1 = *reinterpret_cast<const uint4*>(&Kg[kro + 32 + sc * 8]);
            const size_t vro = vbase + (size_t)srow * TT + kv0;
            vr0 = *reinterpret_cast<const uint4*>(&Vtg[vro + sc * 8]);
            vr1 = *reinterpret_cast<const uint4*>(&Vtg[vro + 32 + sc * 8]);
        }

        for (int i = 0; i < halfL; ++i) {
            *reinterpret_cast<uint4*>(&KsG[srow * 72 + sc * 8])      = kr0;
            *reinterpret_cast<uint4*>(&KsG[srow * 72 + 32 + sc * 8]) = kr1;
            *reinterpret_cast<uint4*>(&VsG[srow * 72 + sc * 8])      = vr0;
            *reinterpret_cast<uint4*>(&VsG[srow * 72 + 32 + sc * 8]) = vr1;
            if (i + 1 < halfL) {
                const size_t kro = base + (size_t)(kv0 + 128 + srow) * DD;
                kr0 = *reinterpret_cast<const uint4*>(&Kg[kro + sc * 8]);
                kr1 = *reinterpret_cast<const uint4*>(&Kg[kro + 32 + sc * 8]);
                const size_t vro = vbase + (size_t)srow * TT + kv0 + 128;
                vr0 = *reinterpret_cast<const uint4*>(&Vtg[vro + sc * 8]);
                vr1 = *reinterpret_cast<const uint4*>(&Vtg[vro + 32 + sc * 8]);
            }
            __syncthreads();

            if (kv0 <= qb + 31) {
                f32x16 sa[2];
#pragma unroll
                for (int st = 0; st < 2; st++)
#pragma unroll
                    for (int r = 0; r < 16; r++) sa[st][r] = 0.f;
                __builtin_amdgcn_s_setprio(1);
#pragma unroll
                for (int st = 0; st < 2; st++)
#pragma unroll
                    for (int ds = 0; ds < 4; ds++) {
                        bf16x8 kf = *reinterpret_cast<const bf16x8*>(
                            &KsG[(st * 32 + ql) * 72 + ds * 16 + hB * 8]);
                        sa[st] = __builtin_amdgcn_mfma_f32_32x32x16_bf16(kf, qf[ds], sa[st], 0, 0, 0);
                    }
                __builtin_amdgcn_s_setprio(0);
                // causal mask only on diagonal tiles (wave-uniform test)
                if (kv0 + 63 > qb) {
#pragma unroll
                    for (int st = 0; st < 2; st++) {
                        const int kb0 = kv0 + st * 32 + 4 * hB;
#pragma unroll
                        for (int r = 0; r < 16; r++) {
                            const int kg = kb0 + (r & 3) + 8 * (r >> 2);
                            if (kg > qg) sa[st][r] = -1e30f;
                        }
                    }
                }
                // tile max (tree) + cross-half
                float mx[16];
#pragma unroll
                for (int j = 0; j < 16; j++) mx[j] = fmaxf(sa[0][j], sa[1][j]);
#pragma unroll
                for (int j = 0; j < 8; j++) mx[j] = fmaxf(mx[j], mx[j + 8]);
#pragma unroll
                for (int j = 0; j < 4; j++) mx[j] = fmaxf(mx[j], mx[j + 4]);
                float tm = fmaxf(fmaxf(mx[0], mx[1]), fmaxf(mx[2], mx[3]));
                tm = fmaxf(tm, __shfl_xor(tm, 32));
                const float mn = fmaxf(m_, tm);
                const bool need = __any(mn > m_);
                float scl = 1.0f;
                if (need) { scl = exp2f(m_ - mn); m_ = mn; }
                // exp (base-2; scale folded into Q)
#pragma unroll
                for (int st = 0; st < 2; st++)
#pragma unroll
                    for (int r = 0; r < 16; r++)
                        sa[st][r] = exp2f(sa[st][r] - m_);
                // row sum (tree) + cross-half
                float ps[16];
#pragma unroll
                for (int j = 0; j < 16; j++) ps[j] = sa[0][j] + sa[1][j];
#pragma unroll
                for (int j = 0; j < 8; j++) ps[j] += ps[j + 8];
#pragma unroll
                for (int j = 0; j < 4; j++) ps[j] += ps[j + 4];
                float rs = (ps[0] + ps[1]) + (ps[2] + ps[3]);
                rs += __shfl_xor(rs, 32);
                if (need) {
                    l_ = l_ * scl + rs;
#pragma unroll
                    for (int dh = 0; dh < 2; dh++)
#pragma unroll
                        for (int r = 0; r < 16; r++) acc[dh][r] *= scl;
                } else {
                    l_ += rs;
                }
                // pack P, permlane to A-frag, PV
                u32 pk[2][8];
#pragma unroll
                for (int st = 0; st < 2; st++)
#pragma unroll
                    for (int wd = 0; wd < 8; wd++)
                        pk[st][wd] = pkbf(sa[st][2 * wd], sa[st][2 * wd + 1]);
                __builtin_amdgcn_s_setprio(1);
#pragma unroll
                for (int c = 0; c < 4; c++) {
                    u32 a0 = pk[c >> 1][4 * (c & 1) + 0];
                    u32 a1 = pk[c >> 1][4 * (c & 1) + 1];
                    u32 a2 = pk[c >> 1][4 * (c & 1) + 2];
                    u32 a3 = pk[c >> 1][4 * (c & 1) + 3];
                    asm volatile("v_permlane32_swap_b32 %0, %1" : "+v"(a0), "+v"(a2));
                    asm volatile("v_permlane32_swap_b32 %0, %1" : "+v"(a1), "+v"(a3));
                    uint4 tw = make_uint4(a0, a1, a2, a3);
                    bf16x8 pb = __builtin_bit_cast(bf16x8, tw);
#pragma unroll
                    for (int dh = 0; dh < 2; dh++) {
                        bf16x8 vf = *reinterpret_cast<const bf16x8*>(
                            &VsG[(dh * 32 + ql) * 72 + c * 16 + hB * 8]);
                        acc[dh] = __builtin_amdgcn_mfma_f32_32x32x16_bf16(vf, pb, acc[dh], 0, 0, 0);
                    }
                }
                __builtin_amdgcn_s_setprio(0);
            }
            __syncthreads();
            kv0 += 128;
        }

        // ---- merge group1 -> group0 via LDS ----
        const int fidx = (wq * 64 + lane) * 36;
        if (g == 1) {
#pragma unroll
            for (int dh = 0; dh < 2; dh++)
#pragma unroll
                for (int r = 0; r < 16; r++) fm[fidx + dh * 16 + r] = acc[dh][r];
            fm[fidx + 32] = m_;
            fm[fidx + 33] = l_;
        }
        __syncthreads();
        float o_sc1 = 0.f, o_sc2 = 0.f, linv = 0.f;
        float acc2[32];
        if (g == 0) {
            const float m2 = fm[fidx + 32];
            const float l2 = fm[fidx + 33];
            const float mm = fmaxf(m_, m2);
            o_sc1 = exp2f(m_ - mm);
            o_sc2 = exp2f(m2 - mm);
            const float lt = l_ * o_sc1 + l2 * o_sc2;
            linv = 1.0f / lt;
#pragma unroll
            for (int dh = 0; dh < 2; dh++)
#pragma unroll
                for (int r = 0; r < 16; r++) acc2[dh * 16 + r] = fm[fidx + dh * 16 + r];
        }
        __syncthreads();
        if (g == 0) {
            const int lrow = wq * 32 + ql;
#pragma unroll
            for (int dh = 0; dh < 2; dh++)
#pragma unroll
                for (int rp = 0; rp < 16; rp += 2) {
                    const int d = (rp & 3) + 8 * (rp >> 2) + 4 * hB + 32 * dh;
                    const float v0 = (acc[dh][rp]     * o_sc1 + acc2[dh * 16 + rp]     * o_sc2) * linv;
                    const float v1 = (acc[dh][rp + 1] * o_sc1 + acc2[dh * 16 + rp + 1] * o_sc2) * linv;
                    *reinterpret_cast<u32*>(&smem[lrow * 72 + d]) = pkbf(v0, v1);
                }
        }
        __syncthreads();
        // coalesced Y write: 128 rows x 64 cols
        {
            const int row = tid >> 2;
            const int ch = tid & 3;
#pragma unroll
            for (int p = 0; p < 2; ++p) {
                uint4 ov = *reinterpret_cast<const uint4*>(&smem[row * 72 + (ch + 4 * p) * 8]);
                *reinterpret_cast<uint4*>(&Y[(size_t)(b * TT + q0 + row) * CC + hh * DD + (ch + 4 * p) * 8]) = ov;
            }
        }
        __syncthreads();
    }
}

extern "C" void kernel_launch(void* const* d_in, const int* in_sizes, int n_in,
                              void* d_out, int out_size, void* d_ws, size_t ws_size,
                              hipStream_t stream)
{
    const float* x     = (const float*)d_in[0];
    const float* Wqkv  = (const float*)d_in[1];
    const float* bqkv  = (const float*)d_in[2];
    const float* Wproj = (const float*)d_in[3];
    const float* bproj = (const float*)d_in[4];
    float* out = (float*)d_out;

    u16* ws     = (u16*)d_ws;
    u16* xb     = ws;
    u16* wqkvb  = xb     + (size_t)MR * CC;
    u16* wprojb = wqkvb  + (size_t)NQ * CC;
    u16* qkv    = wprojb + (size_t)CC * CC;
    u16* Qr     = qkv    + (size_t)MR * NQ;
    u16* Kr     = Qr     + (size_t)BB * HH * TT * DD;
    u16* Vtg    = Kr     + (size_t)BB * HH * TT * DD;
    u16* yb     = Vtg    + (size_t)BB * HH * TT * DD;
    u32* ctr    = (u32*)(yb + (size_t)MR * CC);

    cvt_all<<<dim3(8192), 256, 0, stream>>>(x, Wqkv, Wproj, xb, wqkvb, wprojb, ctr);

    gemm_bt<1><<<dim3(NQ / 128, MR / 128), 256, 0, stream>>>(xb, wqkvb, bqkv, qkv, MR, NQ, CC);

    rope_reorder<<<dim3(BB * TT * HH * 32 / 256), 256, 0, stream>>>(qkv, Qr, Kr);
    vtrans<<<dim3(TT / 64, BB * HH), 64, 0, stream>>>(qkv, Vtg);

    attn_fwd<<<dim3(256), 512, 0, stream>>>(Qr, Kr, Vtg, yb, ctr);

    gemm_bt<0><<<dim3(CC / 128, MR / 128), 256, 0, stream>>>(yb, wprojb, bproj, out, MR, CC, CC);
}

// Round 5
// 212.711 us; speedup vs baseline: 1.7436x; 1.0234x over previous
//
#include <hip/hip_runtime.h>

typedef unsigned short u16;
typedef unsigned int u32;
typedef __bf16 bf16x8 __attribute__((ext_vector_type(8)));
typedef float f32x4 __attribute__((ext_vector_type(4)));
typedef float f32x16 __attribute__((ext_vector_type(16)));

#define BB 2
#define TT 2048
#define CC 1024
#define HH 16
#define DD 64
#define MR (BB*TT)   // 4096
#define NQ (3*CC)    // 3072
#define SCQ 0.18033688f   // 0.125 * log2(e), folded into Q

__device__ __forceinline__ u16 f2b(float f) {
    u32 u = __builtin_bit_cast(u32, f);
    u = (u + 0x7fffu + ((u >> 16) & 1u)) >> 16;
    return (u16)u;
}
__device__ __forceinline__ float b2f(u16 b) {
    return __builtin_bit_cast(float, (u32)b << 16);
}
__device__ __forceinline__ u32 pkbf(float a, float b) {
    ushort2 t; t.x = f2b(a); t.y = f2b(b);
    return __builtin_bit_cast(u32, t);
}

__device__ __forceinline__ void gll16(const void* g, void* l) {
    __builtin_amdgcn_global_load_lds(
        (const __attribute__((address_space(1))) void*)g,
        (__attribute__((address_space(3))) void*)l,
        16, 0, 0);
}

// ------- fused fp32->bf16 convert (x, Wqkv, Wproj) + rope table + counter zero -------
__global__ void cvt_all(const float* __restrict__ x, const float* __restrict__ wqkv,
                        const float* __restrict__ wproj,
                        u16* __restrict__ xb, u16* __restrict__ wqkvb, u16* __restrict__ wprojb,
                        float2* __restrict__ tab, u32* __restrict__ ctr)
{
    if (blockIdx.x == 0 && threadIdx.x == 0) *ctr = 0;
    const int n0 = MR * CC / 4, n1 = NQ * CC / 4, n2 = CC * CC / 4;
    int i = blockIdx.x * 256 + threadIdx.x;
    if (i < n0 + n1 + n2) {
        const float* src; u16* dst; int off;
        if (i < n0)           { src = x;     dst = xb;     off = i; }
        else if (i < n0 + n1) { src = wqkv;  dst = wqkvb;  off = i - n0; }
        else                  { src = wproj; dst = wprojb; off = i - n0 - n1; }
        float4 v = reinterpret_cast<const float4*>(src)[off];
        ushort4 o;
        o.x = f2b(v.x); o.y = f2b(v.y); o.z = f2b(v.z); o.w = f2b(v.w);
        reinterpret_cast<ushort4*>(dst)[off] = o;
    } else {
        const int e = i - (n0 + n1 + n2);
        if (e < TT * 32) {
            const int t = e >> 5, j = e & 31;
            const float theta = expf((float)(2 * j) * (-0.14391157f)); // -ln(1e4)/64
            float s, c;
            sincosf((float)t * theta, &s, &c);
            tab[e] = make_float2(c, s);
        }
    }
}

// ------- QKV GEMM (m97 structure) + fused bias + RoPE + scatter epilogue -------
// A: MR x CC bf16 (x), Bm: NQ x CC bf16 (Wqkv). Writes Qr/Kr in (B,H,T,D) (rope'd,
// Q pre-scaled by SCQ) and V to compact Vc (B,T,C).
__global__ __launch_bounds__(256) void gemm_qkv(
    const u16* __restrict__ A, const u16* __restrict__ Bm,
    const float* __restrict__ bias, const float2* __restrict__ tab,
    u16* __restrict__ Qr, u16* __restrict__ Kr, u16* __restrict__ Vc)
{
    __shared__ __align__(16) u16 As[128 * 32];
    __shared__ __align__(16) u16 Bs[128 * 32];
    const int K = CC;
    const int tid = threadIdx.x;
    const int lane = tid & 63;
    const int w = tid >> 6;
    const int wr = w >> 1, wc = w & 1;
    const int fr = lane & 15, fq = lane >> 4;
    // bijective XCD swizzle: nwg = 768 = 8 * 96
    const int orig = blockIdx.y * 24 + blockIdx.x;
    const int wg = (orig & 7) * 96 + (orig >> 3);
    const int brow = (wg / 24) * 128, bcol = (wg % 24) * 128;
    const int srow = lane >> 2;
    const int scol = (lane & 3) * 8;

    f32x4 acc[4][4];
    const f32x4 zero = {0.f, 0.f, 0.f, 0.f};
#pragma unroll
    for (int i = 0; i < 4; i++)
#pragma unroll
        for (int j = 0; j < 4; j++) acc[i][j] = zero;

    for (int kt = 0; kt < K; kt += 32) {
#pragma unroll
        for (int i = 0; i < 2; i++) {
            const int r = i * 64 + w * 16 + srow;
            gll16(&A[(size_t)(brow + r) * K + kt + scol], &As[(i * 64 + w * 16) * 32]);
            gll16(&Bm[(size_t)(bcol + r) * K + kt + scol], &Bs[(i * 64 + w * 16) * 32]);
        }
        __syncthreads();
        bf16x8 af[4], bfr[4];
#pragma unroll
        for (int mi = 0; mi < 4; mi++)
            af[mi] = *reinterpret_cast<const bf16x8*>(&As[(wr * 64 + mi * 16 + fr) * 32 + fq * 8]);
#pragma unroll
        for (int nj = 0; nj < 4; nj++)
            bfr[nj] = *reinterpret_cast<const bf16x8*>(&Bs[(wc * 64 + nj * 16 + fr) * 32 + fq * 8]);
#pragma unroll
        for (int mi = 0; mi < 4; mi++)
#pragma unroll
            for (int nj = 0; nj < 4; nj++)
                acc[mi][nj] = __builtin_amdgcn_mfma_f32_16x16x32_bf16(af[mi], bfr[nj], acc[mi][nj], 0, 0, 0);
        __syncthreads();
    }

    // epilogue: bias + rope + scatter
#pragma unroll
    for (int mi = 0; mi < 4; mi++) {
#pragma unroll
        for (int nj = 0; nj < 4; nj++) {
            const int n = bcol + wc * 64 + nj * 16 + fr;
            const float bn = bias[n];
            const int sec = n >> 10;          // 0=Q 1=K 2=V (fragment-uniform)
            const int h = (n >> 6) & 15;
            const int d = n & 63;
            const int j = d >> 1;
            const bool odd = d & 1;
#pragma unroll
            for (int r = 0; r < 4; r++) {
                const int m = brow + wr * 64 + mi * 16 + fq * 4 + r;
                const int b = m >> 11, t = m & 2047;
                const float v = acc[mi][nj][r] + bn;
                const float p = __shfl_xor(v, 1);
                if (sec == 2) {
                    Vc[(size_t)m * CC + (n - 2 * CC)] = f2b(v);
                } else {
                    const float2 cs = tab[t * 32 + j];
                    const float o = odd ? (v * cs.x + p * cs.y) : (v * cs.x - p * cs.y);
                    const size_t oidx = ((size_t)(b * HH + h) * TT + t) * DD + d;
                    if (sec == 0) Qr[oidx] = f2b(o * SCQ);
                    else          Kr[oidx] = f2b(o);
                }
            }
        }
    }
}

// ---------------- generic GEMM (m97 structure), used for proj ----------------
template<int BF16_OUT>
__global__ __launch_bounds__(256) void gemm_bt(
    const u16* __restrict__ A, const u16* __restrict__ Bm,
    const float* __restrict__ bias, void* __restrict__ outp,
    int M, int N, int K)
{
    __shared__ __align__(16) u16 As[128 * 32];
    __shared__ __align__(16) u16 Bs[128 * 32];
    const int tid = threadIdx.x;
    const int lane = tid & 63;
    const int w = tid >> 6;
    const int wr = w >> 1, wc = w & 1;
    const int fr = lane & 15, fq = lane >> 4;
    const int brow = blockIdx.y * 128, bcol = blockIdx.x * 128;
    const int srow = lane >> 2;
    const int scol = (lane & 3) * 8;

    f32x4 acc[4][4];
    const f32x4 zero = {0.f, 0.f, 0.f, 0.f};
#pragma unroll
    for (int i = 0; i < 4; i++)
#pragma unroll
        for (int j = 0; j < 4; j++) acc[i][j] = zero;

    for (int kt = 0; kt < K; kt += 32) {
#pragma unroll
        for (int i = 0; i < 2; i++) {
            const int r = i * 64 + w * 16 + srow;
            gll16(&A[(size_t)(brow + r) * K + kt + scol], &As[(i * 64 + w * 16) * 32]);
            gll16(&Bm[(size_t)(bcol + r) * K + kt + scol], &Bs[(i * 64 + w * 16) * 32]);
        }
        __syncthreads();
        bf16x8 af[4], bfr[4];
#pragma unroll
        for (int mi = 0; mi < 4; mi++)
            af[mi] = *reinterpret_cast<const bf16x8*>(&As[(wr * 64 + mi * 16 + fr) * 32 + fq * 8]);
#pragma unroll
        for (int nj = 0; nj < 4; nj++)
            bfr[nj] = *reinterpret_cast<const bf16x8*>(&Bs[(wc * 64 + nj * 16 + fr) * 32 + fq * 8]);
#pragma unroll
        for (int mi = 0; mi < 4; mi++)
#pragma unroll
            for (int nj = 0; nj < 4; nj++)
                acc[mi][nj] = __builtin_amdgcn_mfma_f32_16x16x32_bf16(af[mi], bfr[nj], acc[mi][nj], 0, 0, 0);
        __syncthreads();
    }

#pragma unroll
    for (int mi = 0; mi < 4; mi++) {
#pragma unroll
        for (int nj = 0; nj < 4; nj++) {
            const int n = bcol + wc * 64 + nj * 16 + fr;
            const float bn = bias[n];
#pragma unroll
            for (int r = 0; r < 4; r++) {
                const int m = brow + wr * 64 + mi * 16 + fq * 4 + r;
                const float v = acc[mi][nj][r] + bn;
                if (BF16_OUT) reinterpret_cast<u16*>(outp)[(size_t)m * N + n] = f2b(v);
                else          reinterpret_cast<float*>(outp)[(size_t)m * N + n] = v;
            }
        }
    }
}

// ---------------- V transpose: Vc (B,T,C) -> Vt (B,H,D,T) ----------------
__global__ __launch_bounds__(64) void vtrans(const u16* __restrict__ Vc, u16* __restrict__ Vtg)
{
    const int lane = threadIdx.x;
    const int t0 = blockIdx.x * 64;
    const int bh = blockIdx.y;
    const int b = bh >> 4, h = bh & 15;
    u32 packed[32];
#pragma unroll
    for (int tt = 0; tt < 64; tt += 2) {
        const u16 a = Vc[(size_t)(b * TT + t0 + tt) * CC + h * DD + lane];
        const u16 c = Vc[(size_t)(b * TT + t0 + tt + 1) * CC + h * DD + lane];
        packed[tt >> 1] = (u32)a | ((u32)c << 16);
    }
    u32* dst = reinterpret_cast<u32*>(&Vtg[((size_t)bh * DD + lane) * TT + t0]);
#pragma unroll
    for (int i = 0; i < 32; i += 4)
        *reinterpret_cast<uint4*>(&dst[i]) = make_uint4(packed[i], packed[i + 1], packed[i + 2], packed[i + 3]);
}

// ---------------- causal flash attention: persistent + queue + KV-split ----------------
__global__ __launch_bounds__(512) void attn_fwd(
    const u16* __restrict__ Q, const u16* __restrict__ Kg, const u16* __restrict__ Vtg,
    u16* __restrict__ Y, u32* __restrict__ ctr)
{
    __shared__ __align__(16) u16 smem[4 * 64 * 72];
    __shared__ int cur;
    const int tid = threadIdx.x;
    const int lane = tid & 63;
    const int ql = lane & 31;
    const int hB = lane >> 5;
    const int wq = (tid >> 6) & 3;
    const int g  = tid >> 8;
    const int srow = (tid & 255) >> 2;
    const int sc   = tid & 3;
    u16* KsG = smem + (g * 2 + 0) * 4608;
    u16* VsG = smem + (g * 2 + 1) * 4608;
    float* fm = reinterpret_cast<float*>(smem);

    while (true) {
        if (tid == 0) cur = atomicAdd(ctr, 1);
        __syncthreads();
        const int it = cur;
        __syncthreads();
        if (it >= 512) break;

        const int bx = 15 - (it >> 5);
        const int bh = it & 31;
        const int q0 = bx << 7;
        const int halfL = bx + 1;
        const int b = bh >> 4, hh = bh & 15;
        const int qb = q0 + wq * 32;
        const int qg = qb + ql;
        const size_t base  = (size_t)bh * TT * DD;
        const size_t vbase = (size_t)bh * DD * TT;

        bf16x8 qf[4];
#pragma unroll
        for (int ds = 0; ds < 4; ds++)
            qf[ds] = *reinterpret_cast<const bf16x8*>(&Q[base + (size_t)qg * DD + ds * 16 + hB * 8]);

        f32x16 acc[2];
#pragma unroll
        for (int dh = 0; dh < 2; dh++)
#pragma unroll
            for (int r = 0; r < 16; r++) acc[dh][r] = 0.f;
        float m_ = -1e30f, l_ = 0.f;

        int kv0 = 64 * g;
        uint4 kr0, kr1, vr0, vr1;
        {
            const size_t kro = base + (size_t)(kv0 + srow) * DD;
            kr0 = *reinterpret_cast<const uint4*>(&Kg[kro + sc * 8]);
            kr1 = *reinterpret_cast<const uint4*>(&Kg[kro + 32 + sc * 8]);
            const size_t vro = vbase + (size_t)srow * TT + kv0;
            vr0 = *reinterpret_cast<const uint4*>(&Vtg[vro + sc * 8]);
            vr1 = *reinterpret_cast<const uint4*>(&Vtg[vro + 32 + sc * 8]);
        }

        for (int i = 0; i < halfL; ++i) {
            *reinterpret_cast<uint4*>(&KsG[srow * 72 + sc * 8])      = kr0;
            *reinterpret_cast<uint4*>(&KsG[srow * 72 + 32 + sc * 8]) = kr1;
            *reinterpret_cast<uint4*>(&VsG[srow * 72 + sc * 8])      = vr0;
            *reinterpret_cast<uint4*>(&VsG[srow * 72 + 32 + sc * 8]) = vr1;
            if (i + 1 < halfL) {
                const size_t kro = base + (size_t)(kv0 + 128 + srow) * DD;
                kr0 = *reinterpret_cast<const uint4*>(&Kg[kro + sc * 8]);
                kr1 = *reinterpret_cast<const uint4*>(&Kg[kro + 32 + sc * 8]);
                const size_t vro = vbase + (size_t)srow * TT + kv0 + 128;
                vr0 = *reinterpret_cast<const uint4*>(&Vtg[vro + sc * 8]);
                vr1 = *reinterpret_cast<const uint4*>(&Vtg[vro + 32 + sc * 8]);
            }
            __syncthreads();

            if (kv0 <= qb + 31) {
                f32x16 sa[2];
#pragma unroll
                for (int st = 0; st < 2; st++)
#pragma unroll
                    for (int r = 0; r < 16; r++) sa[st][r] = 0.f;
                __builtin_amdgcn_s_setprio(1);
#pragma unroll
                for (int st = 0; st < 2; st++)
#pragma unroll
                    for (int ds = 0; ds < 4; ds++) {
                        bf16x8 kf = *reinterpret_cast<const bf16x8*>(
                            &KsG[(st * 32 + ql) * 72 + ds * 16 + hB * 8]);
                        sa[st] = __builtin_amdgcn_mfma_f32_32x32x16_bf16(kf, qf[ds], sa[st], 0, 0, 0);
                    }
                __builtin_amdgcn_s_setprio(0);
                if (kv0 + 63 > qb) {
#pragma unroll
                    for (int st = 0; st < 2; st++) {
                        const int kb0 = kv0 + st * 32 + 4 * hB;
#pragma unroll
                        for (int r = 0; r < 16; r++) {
                            const int kg = kb0 + (r & 3) + 8 * (r >> 2);
                            if (kg > qg) sa[st][r] = -1e30f;
                        }
                    }
                }
                float mx[16];
#pragma unroll
                for (int j = 0; j < 16; j++) mx[j] = fmaxf(sa[0][j], sa[1][j]);
#pragma unroll
                for (int j = 0; j < 8; j++) mx[j] = fmaxf(mx[j], mx[j + 8]);
#pragma unroll
                for (int j = 0; j < 4; j++) mx[j] = fmaxf(mx[j], mx[j + 4]);
                float tm = fmaxf(fmaxf(mx[0], mx[1]), fmaxf(mx[2], mx[3]));
                tm = fmaxf(tm, __shfl_xor(tm, 32));
                const float mn = fmaxf(m_, tm);
                const bool need = __any(mn > m_);
                float scl = 1.0f;
                if (need) { scl = exp2f(m_ - mn); m_ = mn; }
#pragma unroll
                for (int st = 0; st < 2; st++)
#pragma unroll
                    for (int r = 0; r < 16; r++)
                        sa[st][r] = exp2f(sa[st][r] - m_);
                float ps[16];
#pragma unroll
                for (int j = 0; j < 16; j++) ps[j] = sa[0][j] + sa[1][j];
#pragma unroll
                for (int j = 0; j < 8; j++) ps[j] += ps[j + 8];
#pragma unroll
                for (int j = 0; j < 4; j++) ps[j] += ps[j + 4];
                float rs = (ps[0] + ps[1]) + (ps[2] + ps[3]);
                rs += __shfl_xor(rs, 32);
                if (need) {
                    l_ = l_ * scl + rs;
#pragma unroll
                    for (int dh = 0; dh < 2; dh++)
#pragma unroll
                        for (int r = 0; r < 16; r++) acc[dh][r] *= scl;
                } else {
                    l_ += rs;
                }
                u32 pk[2][8];
#pragma unroll
                for (int st = 0; st < 2; st++)
#pragma unroll
                    for (int wd = 0; wd < 8; wd++)
                        pk[st][wd] = pkbf(sa[st][2 * wd], sa[st][2 * wd + 1]);
                __builtin_amdgcn_s_setprio(1);
#pragma unroll
                for (int c = 0; c < 4; c++) {
                    u32 a0 = pk[c >> 1][4 * (c & 1) + 0];
                    u32 a1 = pk[c >> 1][4 * (c & 1) + 1];
                    u32 a2 = pk[c >> 1][4 * (c & 1) + 2];
                    u32 a3 = pk[c >> 1][4 * (c & 1) + 3];
                    asm volatile("v_permlane32_swap_b32 %0, %1" : "+v"(a0), "+v"(a2));
                    asm volatile("v_permlane32_swap_b32 %0, %1" : "+v"(a1), "+v"(a3));
                    uint4 tw = make_uint4(a0, a1, a2, a3);
                    bf16x8 pb = __builtin_bit_cast(bf16x8, tw);
#pragma unroll
                    for (int dh = 0; dh < 2; dh++) {
                        bf16x8 vf = *reinterpret_cast<const bf16x8*>(
                            &VsG[(dh * 32 + ql) * 72 + c * 16 + hB * 8]);
                        acc[dh] = __builtin_amdgcn_mfma_f32_32x32x16_bf16(vf, pb, acc[dh], 0, 0, 0);
                    }
                }
                __builtin_amdgcn_s_setprio(0);
            }
            __syncthreads();
            kv0 += 128;
        }

        const int fidx = (wq * 64 + lane) * 36;
        if (g == 1) {
#pragma unroll
            for (int dh = 0; dh < 2; dh++)
#pragma unroll
                for (int r = 0; r < 16; r++) fm[fidx + dh * 16 + r] = acc[dh][r];
            fm[fidx + 32] = m_;
            fm[fidx + 33] = l_;
        }
        __syncthreads();
        float o_sc1 = 0.f, o_sc2 = 0.f, linv = 0.f;
        float acc2[32];
        if (g == 0) {
            const float m2 = fm[fidx + 32];
            const float l2 = fm[fidx + 33];
            const float mm = fmaxf(m_, m2);
            o_sc1 = exp2f(m_ - mm);
            o_sc2 = exp2f(m2 - mm);
            const float lt = l_ * o_sc1 + l2 * o_sc2;
            linv = 1.0f / lt;
#pragma unroll
            for (int dh = 0; dh < 2; dh++)
#pragma unroll
                for (int r = 0; r < 16; r++) acc2[dh * 16 + r] = fm[fidx + dh * 16 + r];
        }
        __syncthreads();
        if (g == 0) {
            const int lrow = wq * 32 + ql;
#pragma unroll
            for (int dh = 0; dh < 2; dh++)
#pragma unroll
                for (int rp = 0; rp < 16; rp += 2) {
                    const int d = (rp & 3) + 8 * (rp >> 2) + 4 * hB + 32 * dh;
                    const float v0 = (acc[dh][rp]     * o_sc1 + acc2[dh * 16 + rp]     * o_sc2) * linv;
                    const float v1 = (acc[dh][rp + 1] * o_sc1 + acc2[dh * 16 + rp + 1] * o_sc2) * linv;
                    *reinterpret_cast<u32*>(&smem[lrow * 72 + d]) = pkbf(v0, v1);
                }
        }
        __syncthreads();
        {
            const int row = tid >> 2;
            const int ch = tid & 3;
#pragma unroll
            for (int p = 0; p < 2; ++p) {
                uint4 ov = *reinterpret_cast<const uint4*>(&smem[row * 72 + (ch + 4 * p) * 8]);
                *reinterpret_cast<uint4*>(&Y[(size_t)(b * TT + q0 + row) * CC + hh * DD + (ch + 4 * p) * 8]) = ov;
            }
        }
        __syncthreads();
    }
}

extern "C" void kernel_launch(void* const* d_in, const int* in_sizes, int n_in,
                              void* d_out, int out_size, void* d_ws, size_t ws_size,
                              hipStream_t stream)
{
    const float* x     = (const float*)d_in[0];
    const float* Wqkv  = (const float*)d_in[1];
    const float* bqkv  = (const float*)d_in[2];
    const float* Wproj = (const float*)d_in[3];
    const float* bproj = (const float*)d_in[4];
    float* out = (float*)d_out;

    u16* ws     = (u16*)d_ws;
    u16* xb     = ws;                                  // 4M u16
    u16* wqkvb  = xb     + (size_t)MR * CC;            // 3M
    u16* wprojb = wqkvb  + (size_t)NQ * CC;            // 1M
    u16* Vc     = wprojb + (size_t)CC * CC;            // 4M  (B,T,C) V section
    u16* Qr     = Vc     + (size_t)MR * CC;            // 4M  (B,H,T,D)
    u16* Kr     = Qr     + (size_t)BB * HH * TT * DD;  // 4M
    u16* Vtg    = Kr     + (size_t)BB * HH * TT * DD;  // 4M  (B,H,D,T)
    u16* yb     = Vtg    + (size_t)BB * HH * TT * DD;  // 4M
    float2* tab = (float2*)(yb + (size_t)MR * CC);     // 2048*32 float2
    u32* ctr    = (u32*)(tab + (size_t)TT * 32);

    cvt_all<<<dim3(8448), 256, 0, stream>>>(x, Wqkv, Wproj, xb, wqkvb, wprojb, tab, ctr);

    gemm_qkv<<<dim3(24, 32), 256, 0, stream>>>(xb, wqkvb, bqkv, tab, Qr, Kr, Vc);

    vtrans<<<dim3(TT / 64, BB * HH), 64, 0, stream>>>(Vc, Vtg);

    attn_fwd<<<dim3(256), 512, 0, stream>>>(Qr, Kr, Vtg, yb, ctr);

    gemm_bt<0><<<dim3(CC / 128, MR / 128), 256, 0, stream>>>(yb, wprojb, bproj, out, MR, CC, CC);
}

// Round 6
// 202.349 us; speedup vs baseline: 1.8329x; 1.0512x over previous
//
#include <hip/hip_runtime.h>

typedef unsigned short u16;
typedef unsigned int u32;
typedef __bf16 bf16x2 __attribute__((ext_vector_type(2)));
typedef __bf16 bf16x8 __attribute__((ext_vector_type(8)));
typedef float f32x4 __attribute__((ext_vector_type(4)));
typedef float f32x16 __attribute__((ext_vector_type(16)));

#define BB 2
#define TT 2048
#define CC 1024
#define HH 16
#define DD 64
#define MR (BB*TT)   // 4096
#define NQ (3*CC)    // 3072
#define SCQ 0.18033688f   // 0.125 * log2(e), folded into Q

__device__ __forceinline__ u16 f2b(float f) {
    __bf16 h = (__bf16)f;
    return __builtin_bit_cast(u16, h);
}
__device__ __forceinline__ float b2f(u16 b) {
    return __builtin_bit_cast(float, (u32)b << 16);
}
__device__ __forceinline__ u32 pkbf(float a, float b) {
    bf16x2 t; t[0] = (__bf16)a; t[1] = (__bf16)b;
    return __builtin_bit_cast(u32, t);
}

__device__ __forceinline__ void gll16(const void* g, void* l) {
    __builtin_amdgcn_global_load_lds(
        (const __attribute__((address_space(1))) void*)g,
        (__attribute__((address_space(3))) void*)l,
        16, 0, 0);
}

// ------- fused fp32->bf16 convert (x, Wqkv, Wproj) + rope table + counter zero -------
__global__ void cvt_all(const float* __restrict__ x, const float* __restrict__ wqkv,
                        const float* __restrict__ wproj,
                        u16* __restrict__ xb, u16* __restrict__ wqkvb, u16* __restrict__ wprojb,
                        float2* __restrict__ tab, u32* __restrict__ ctr)
{
    if (blockIdx.x == 0 && threadIdx.x == 0) *ctr = 0;
    const int n0 = MR * CC / 4, n1 = NQ * CC / 4, n2 = CC * CC / 4;
    int i = blockIdx.x * 256 + threadIdx.x;
    if (i < n0 + n1 + n2) {
        const float* src; u16* dst; int off;
        if (i < n0)           { src = x;     dst = xb;     off = i; }
        else if (i < n0 + n1) { src = wqkv;  dst = wqkvb;  off = i - n0; }
        else                  { src = wproj; dst = wprojb; off = i - n0 - n1; }
        float4 v = reinterpret_cast<const float4*>(src)[off];
        ushort4 o;
        o.x = f2b(v.x); o.y = f2b(v.y); o.z = f2b(v.z); o.w = f2b(v.w);
        reinterpret_cast<ushort4*>(dst)[off] = o;
    } else {
        const int e = i - (n0 + n1 + n2);
        if (e < TT * 32) {
            const int t = e >> 5, j = e & 31;
            const float theta = expf((float)(2 * j) * (-0.14391157f)); // -ln(1e4)/64
            float s, c;
            sincosf((float)t * theta, &s, &c);
            tab[e] = make_float2(c, s);
        }
    }
}

// ------- QKV GEMM (m97 structure) + fused bias + RoPE + scatter epilogue -------
__global__ __launch_bounds__(256) void gemm_qkv(
    const u16* __restrict__ A, const u16* __restrict__ Bm,
    const float* __restrict__ bias, const float2* __restrict__ tab,
    u16* __restrict__ Qr, u16* __restrict__ Kr, u16* __restrict__ Vc)
{
    __shared__ __align__(16) u16 As[128 * 32];
    __shared__ __align__(16) u16 Bs[128 * 32];
    const int K = CC;
    const int tid = threadIdx.x;
    const int lane = tid & 63;
    const int w = tid >> 6;
    const int wr = w >> 1, wc = w & 1;
    const int fr = lane & 15, fq = lane >> 4;
    // bijective XCD swizzle: nwg = 768 = 8 * 96
    const int orig = blockIdx.y * 24 + blockIdx.x;
    const int wg = (orig & 7) * 96 + (orig >> 3);
    const int brow = (wg / 24) * 128, bcol = (wg % 24) * 128;
    const int srow = lane >> 2;
    const int scol = (lane & 3) * 8;

    f32x4 acc[4][4];
    const f32x4 zero = {0.f, 0.f, 0.f, 0.f};
#pragma unroll
    for (int i = 0; i < 4; i++)
#pragma unroll
        for (int j = 0; j < 4; j++) acc[i][j] = zero;

    for (int kt = 0; kt < K; kt += 32) {
#pragma unroll
        for (int i = 0; i < 2; i++) {
            const int r = i * 64 + w * 16 + srow;
            gll16(&A[(size_t)(brow + r) * K + kt + scol], &As[(i * 64 + w * 16) * 32]);
            gll16(&Bm[(size_t)(bcol + r) * K + kt + scol], &Bs[(i * 64 + w * 16) * 32]);
        }
        __syncthreads();
        bf16x8 af[4], bfr[4];
#pragma unroll
        for (int mi = 0; mi < 4; mi++)
            af[mi] = *reinterpret_cast<const bf16x8*>(&As[(wr * 64 + mi * 16 + fr) * 32 + fq * 8]);
#pragma unroll
        for (int nj = 0; nj < 4; nj++)
            bfr[nj] = *reinterpret_cast<const bf16x8*>(&Bs[(wc * 64 + nj * 16 + fr) * 32 + fq * 8]);
#pragma unroll
        for (int mi = 0; mi < 4; mi++)
#pragma unroll
            for (int nj = 0; nj < 4; nj++)
                acc[mi][nj] = __builtin_amdgcn_mfma_f32_16x16x32_bf16(af[mi], bfr[nj], acc[mi][nj], 0, 0, 0);
        __syncthreads();
    }

    // epilogue: bias + rope + scatter
#pragma unroll
    for (int mi = 0; mi < 4; mi++) {
#pragma unroll
        for (int nj = 0; nj < 4; nj++) {
            const int n = bcol + wc * 64 + nj * 16 + fr;
            const float bn = bias[n];
            const int sec = n >> 10;          // 0=Q 1=K 2=V (fragment-uniform)
            const int h = (n >> 6) & 15;
            const int d = n & 63;
            const int j = d >> 1;
            const bool odd = d & 1;
#pragma unroll
            for (int r = 0; r < 4; r++) {
                const int m = brow + wr * 64 + mi * 16 + fq * 4 + r;
                const int b = m >> 11, t = m & 2047;
                const float v = acc[mi][nj][r] + bn;
                const float p = __shfl_xor(v, 1);
                if (sec == 2) {
                    Vc[(size_t)m * CC + (n - 2 * CC)] = f2b(v);
                } else {
                    const float2 cs = tab[t * 32 + j];
                    const float o = odd ? (v * cs.x + p * cs.y) : (v * cs.x - p * cs.y);
                    const size_t oidx = ((size_t)(b * HH + h) * TT + t) * DD + d;
                    if (sec == 0) Qr[oidx] = f2b(o * SCQ);
                    else          Kr[oidx] = f2b(o);
                }
            }
        }
    }
}

// ------- proj GEMM: 64x128 tile (2 blocks/CU to hide barrier drain), fp32 out -------
// A: M x K bf16 row-major (yb), Bm: N x K bf16 row-major (Wproj). M=4096 N=1024 K=1024.
__global__ __launch_bounds__(256) void gemm_proj(
    const u16* __restrict__ A, const u16* __restrict__ Bm,
    const float* __restrict__ bias, float* __restrict__ outp)
{
    __shared__ __align__(16) u16 As[64 * 32];
    __shared__ __align__(16) u16 Bs[128 * 32];
    const int M = MR, N = CC, K = CC;
    const int tid = threadIdx.x;
    const int lane = tid & 63;
    const int w = tid >> 6;
    const int fr = lane & 15, fq = lane >> 4;
    // bijective XCD swizzle: nwg = 512 = 8 * 64
    const int orig = blockIdx.y * 8 + blockIdx.x;
    const int wg = (orig & 7) * 64 + (orig >> 3);
    const int brow = (wg >> 3) * 64, bcol = (wg & 7) * 128;
    const int srow = lane >> 2;
    const int scol = (lane & 3) * 8;

    f32x4 acc[4][2];
    const f32x4 zero = {0.f, 0.f, 0.f, 0.f};
#pragma unroll
    for (int i = 0; i < 4; i++)
#pragma unroll
        for (int j = 0; j < 2; j++) acc[i][j] = zero;

    for (int kt = 0; kt < K; kt += 32) {
        gll16(&A[(size_t)(brow + w * 16 + srow) * K + kt + scol], &As[(w * 16) * 32]);
#pragma unroll
        for (int i = 0; i < 2; i++)
            gll16(&Bm[(size_t)(bcol + i * 64 + w * 16 + srow) * K + kt + scol],
                  &Bs[(i * 64 + w * 16) * 32]);
        __syncthreads();
        bf16x8 af[4], bfr[2];
#pragma unroll
        for (int mi = 0; mi < 4; mi++)
            af[mi] = *reinterpret_cast<const bf16x8*>(&As[(mi * 16 + fr) * 32 + fq * 8]);
#pragma unroll
        for (int nj = 0; nj < 2; nj++)
            bfr[nj] = *reinterpret_cast<const bf16x8*>(&Bs[(w * 32 + nj * 16 + fr) * 32 + fq * 8]);
#pragma unroll
        for (int mi = 0; mi < 4; mi++)
#pragma unroll
            for (int nj = 0; nj < 2; nj++)
                acc[mi][nj] = __builtin_amdgcn_mfma_f32_16x16x32_bf16(af[mi], bfr[nj], acc[mi][nj], 0, 0, 0);
        __syncthreads();
    }

#pragma unroll
    for (int mi = 0; mi < 4; mi++) {
#pragma unroll
        for (int nj = 0; nj < 2; nj++) {
            const int n = bcol + w * 32 + nj * 16 + fr;
            const float bn = bias[n];
#pragma unroll
            for (int r = 0; r < 4; r++) {
                const int m = brow + mi * 16 + fq * 4 + r;
                outp[(size_t)m * N + n] = acc[mi][nj][r] + bn;
            }
        }
    }
}

// ---------------- V transpose: Vc (B,T,C) -> Vt (B,H,D,T) ----------------
__global__ __launch_bounds__(64) void vtrans(const u16* __restrict__ Vc, u16* __restrict__ Vtg)
{
    const int lane = threadIdx.x;
    const int t0 = blockIdx.x * 64;
    const int bh = blockIdx.y;
    const int b = bh >> 4, h = bh & 15;
    u32 packed[32];
#pragma unroll
    for (int tt = 0; tt < 64; tt += 2) {
        const u16 a = Vc[(size_t)(b * TT + t0 + tt) * CC + h * DD + lane];
        const u16 c = Vc[(size_t)(b * TT + t0 + tt + 1) * CC + h * DD + lane];
        packed[tt >> 1] = (u32)a | ((u32)c << 16);
    }
    u32* dst = reinterpret_cast<u32*>(&Vtg[((size_t)bh * DD + lane) * TT + t0]);
#pragma unroll
    for (int i = 0; i < 32; i += 4)
        *reinterpret_cast<uint4*>(&dst[i]) = make_uint4(packed[i], packed[i + 1], packed[i + 2], packed[i + 3]);
}

// ---------------- causal flash attention: persistent + queue + KV-split ----------------
__global__ __launch_bounds__(512) void attn_fwd(
    const u16* __restrict__ Q, const u16* __restrict__ Kg, const u16* __restrict__ Vtg,
    u16* __restrict__ Y, u32* __restrict__ ctr)
{
    __shared__ __align__(16) u16 smem[4 * 64 * 72];
    __shared__ int cur;
    const int tid = threadIdx.x;
    const int lane = tid & 63;
    const int ql = lane & 31;
    const int hB = lane >> 5;
    const int wq = (tid >> 6) & 3;
    const int g  = tid >> 8;
    const int srow = (tid & 255) >> 2;
    const int sc   = tid & 3;
    u16* KsG = smem + (g * 2 + 0) * 4608;
    u16* VsG = smem + (g * 2 + 1) * 4608;
    float* fm = reinterpret_cast<float*>(smem);

    while (true) {
        if (tid == 0) cur = atomicAdd(ctr, 1);
        __syncthreads();
        const int it = cur;
        __syncthreads();
        if (it >= 512) break;

        const int bx = 15 - (it >> 5);
        const int bh = it & 31;
        const int q0 = bx << 7;
        const int halfL = bx + 1;
        const int b = bh >> 4, hh = bh & 15;
        const int qb = q0 + wq * 32;
        const int qg = qb + ql;
        const size_t base  = (size_t)bh * TT * DD;
        const size_t vbase = (size_t)bh * DD * TT;

        bf16x8 qf[4];
#pragma unroll
        for (int ds = 0; ds < 4; ds++)
            qf[ds] = *reinterpret_cast<const bf16x8*>(&Q[base + (size_t)qg * DD + ds * 16 + hB * 8]);

        f32x16 acc[2];
#pragma unroll
        for (int dh = 0; dh < 2; dh++)
#pragma unroll
            for (int r = 0; r < 16; r++) acc[dh][r] = 0.f;
        float m_ = -1e30f, l_ = 0.f;

        int kv0 = 64 * g;
        uint4 kr0, kr1, vr0, vr1;
        {
            const size_t kro = base + (size_t)(kv0 + srow) * DD;
            kr0 = *reinterpret_cast<const uint4*>(&Kg[kro + sc * 8]);
            kr1 = *reinterpret_cast<const uint4*>(&Kg[kro + 32 + sc * 8]);
            const size_t vro = vbase + (size_t)srow * TT + kv0;
            vr0 = *reinterpret_cast<const uint4*>(&Vtg[vro + sc * 8]);
            vr1 = *reinterpret_cast<const uint4*>(&Vtg[vro + 32 + sc * 8]);
        }

        for (int i = 0; i < halfL; ++i) {
            *reinterpret_cast<uint4*>(&KsG[srow * 72 + sc * 8])      = kr0;
            *reinterpret_cast<uint4*>(&KsG[srow * 72 + 32 + sc * 8]) = kr1;
            *reinterpret_cast<uint4*>(&VsG[srow * 72 + sc * 8])      = vr0;
            *reinterpret_cast<uint4*>(&VsG[srow * 72 + 32 + sc * 8]) = vr1;
            if (i + 1 < halfL) {
                const size_t kro = base + (size_t)(kv0 + 128 + srow) * DD;
                kr0 = *reinterpret_cast<const uint4*>(&Kg[kro + sc * 8]);
                kr1 = *reinterpret_cast<const uint4*>(&Kg[kro + 32 + sc * 8]);
                const size_t vro = vbase + (size_t)srow * TT + kv0 + 128;
                vr0 = *reinterpret_cast<const uint4*>(&Vtg[vro + sc * 8]);
                vr1 = *reinterpret_cast<const uint4*>(&Vtg[vro + 32 + sc * 8]);
            }
            __syncthreads();

            if (kv0 <= qb + 31) {
                f32x16 sa[2];
#pragma unroll
                for (int st = 0; st < 2; st++)
#pragma unroll
                    for (int r = 0; r < 16; r++) sa[st][r] = 0.f;
                __builtin_amdgcn_s_setprio(1);
#pragma unroll
                for (int st = 0; st < 2; st++)
#pragma unroll
                    for (int ds = 0; ds < 4; ds++) {
                        bf16x8 kf = *reinterpret_cast<const bf16x8*>(
                            &KsG[(st * 32 + ql) * 72 + ds * 16 + hB * 8]);
                        sa[st] = __builtin_amdgcn_mfma_f32_32x32x16_bf16(kf, qf[ds], sa[st], 0, 0, 0);
                    }
                __builtin_amdgcn_s_setprio(0);
                if (kv0 + 63 > qb) {
#pragma unroll
                    for (int st = 0; st < 2; st++) {
                        const int kb0 = kv0 + st * 32 + 4 * hB;
#pragma unroll
                        for (int r = 0; r < 16; r++) {
                            const int kg = kb0 + (r & 3) + 8 * (r >> 2);
                            if (kg > qg) sa[st][r] = -1e30f;
                        }
                    }
                }
                // row max: pairwise then max3-shaped tree (v_max3_f32 fusion)
                float mx[16];
#pragma unroll
                for (int j = 0; j < 16; j++) mx[j] = fmaxf(sa[0][j], sa[1][j]);
                const float r0 = fmaxf(fmaxf(mx[0], mx[1]), mx[2]);
                const float r1 = fmaxf(fmaxf(mx[3], mx[4]), mx[5]);
                const float r2 = fmaxf(fmaxf(mx[6], mx[7]), mx[8]);
                const float r3 = fmaxf(fmaxf(mx[9], mx[10]), mx[11]);
                const float r4 = fmaxf(fmaxf(mx[12], mx[13]), mx[14]);
                const float r5 = fmaxf(fmaxf(r0, r1), r2);
                const float r6 = fmaxf(fmaxf(r3, r4), mx[15]);
                float tm = fmaxf(r5, r6);
                tm = fmaxf(tm, __shfl_xor(tm, 32));
                const float mn = fmaxf(m_, tm);
                const bool need = __any(mn > m_);
                float scl = 1.0f;
                if (need) { scl = exp2f(m_ - mn); m_ = mn; }
#pragma unroll
                for (int st = 0; st < 2; st++)
#pragma unroll
                    for (int r = 0; r < 16; r++)
                        sa[st][r] = exp2f(sa[st][r] - m_);
                float ps[16];
#pragma unroll
                for (int j = 0; j < 16; j++) ps[j] = sa[0][j] + sa[1][j];
#pragma unroll
                for (int j = 0; j < 8; j++) ps[j] += ps[j + 8];
#pragma unroll
                for (int j = 0; j < 4; j++) ps[j] += ps[j + 4];
                float rs = (ps[0] + ps[1]) + (ps[2] + ps[3]);
                rs += __shfl_xor(rs, 32);
                if (need) {
                    l_ = l_ * scl + rs;
#pragma unroll
                    for (int dh = 0; dh < 2; dh++)
#pragma unroll
                        for (int r = 0; r < 16; r++) acc[dh][r] *= scl;
                } else {
                    l_ += rs;
                }
                // pack P (native cvt_pk) then permlane to A-frag, PV
                u32 pk[2][8];
#pragma unroll
                for (int st = 0; st < 2; st++)
#pragma unroll
                    for (int wd = 0; wd < 8; wd++)
                        pk[st][wd] = pkbf(sa[st][2 * wd], sa[st][2 * wd + 1]);
                __builtin_amdgcn_s_setprio(1);
#pragma unroll
                for (int c = 0; c < 4; c++) {
                    u32 a0 = pk[c >> 1][4 * (c & 1) + 0];
                    u32 a1 = pk[c >> 1][4 * (c & 1) + 1];
                    u32 a2 = pk[c >> 1][4 * (c & 1) + 2];
                    u32 a3 = pk[c >> 1][4 * (c & 1) + 3];
                    asm volatile("v_permlane32_swap_b32 %0, %1" : "+v"(a0), "+v"(a2));
                    asm volatile("v_permlane32_swap_b32 %0, %1" : "+v"(a1), "+v"(a3));
                    uint4 tw = make_uint4(a0, a1, a2, a3);
                    bf16x8 pb = __builtin_bit_cast(bf16x8, tw);
#pragma unroll
                    for (int dh = 0; dh < 2; dh++) {
                        bf16x8 vf = *reinterpret_cast<const bf16x8*>(
                            &VsG[(dh * 32 + ql) * 72 + c * 16 + hB * 8]);
                        acc[dh] = __builtin_amdgcn_mfma_f32_32x32x16_bf16(vf, pb, acc[dh], 0, 0, 0);
                    }
                }
                __builtin_amdgcn_s_setprio(0);
            }
            __syncthreads();
            kv0 += 128;
        }

        const int fidx = (wq * 64 + lane) * 36;
        if (g == 1) {
#pragma unroll
            for (int dh = 0; dh < 2; dh++)
#pragma unroll
                for (int r = 0; r < 16; r++) fm[fidx + dh * 16 + r] = acc[dh][r];
            fm[fidx + 32] = m_;
            fm[fidx + 33] = l_;
        }
        __syncthreads();
        float o_sc1 = 0.f, o_sc2 = 0.f, linv = 0.f;
        float acc2[32];
        if (g == 0) {
            const float m2 = fm[fidx + 32];
            const float l2 = fm[fidx + 33];
            const float mm = fmaxf(m_, m2);
            o_sc1 = exp2f(m_ - mm);
            o_sc2 = exp2f(m2 - mm);
            const float lt = l_ * o_sc1 + l2 * o_sc2;
            linv = 1.0f / lt;
#pragma unroll
            for (int dh = 0; dh < 2; dh++)
#pragma unroll
                for (int r = 0; r < 16; r++) acc2[dh * 16 + r] = fm[fidx + dh * 16 + r];
        }
        __syncthreads();
        if (g == 0) {
            const int lrow = wq * 32 + ql;
#pragma unroll
            for (int dh = 0; dh < 2; dh++)
#pragma unroll
                for (int rp = 0; rp < 16; rp += 2) {
                    const int d = (rp & 3) + 8 * (rp >> 2) + 4 * hB + 32 * dh;
                    const float v0 = (acc[dh][rp]     * o_sc1 + acc2[dh * 16 + rp]     * o_sc2) * linv;
                    const float v1 = (acc[dh][rp + 1] * o_sc1 + acc2[dh * 16 + rp + 1] * o_sc2) * linv;
                    *reinterpret_cast<u32*>(&smem[lrow * 72 + d]) = pkbf(v0, v1);
                }
        }
        __syncthreads();
        {
            const int row = tid >> 2;
            const int ch = tid & 3;
#pragma unroll
            for (int p = 0; p < 2; ++p) {
                uint4 ov = *reinterpret_cast<const uint4*>(&smem[row * 72 + (ch + 4 * p) * 8]);
                *reinterpret_cast<uint4*>(&Y[(size_t)(b * TT + q0 + row) * CC + hh * DD + (ch + 4 * p) * 8]) = ov;
            }
        }
        __syncthreads();
    }
}

extern "C" void kernel_launch(void* const* d_in, const int* in_sizes, int n_in,
                              void* d_out, int out_size, void* d_ws, size_t ws_size,
                              hipStream_t stream)
{
    const float* x     = (const float*)d_in[0];
    const float* Wqkv  = (const float*)d_in[1];
    const float* bqkv  = (const float*)d_in[2];
    const float* Wproj = (const float*)d_in[3];
    const float* bproj = (const float*)d_in[4];
    float* out = (float*)d_out;

    u16* ws     = (u16*)d_ws;
    u16* xb     = ws;                                  // 4M u16
    u16* wqkvb  = xb     + (size_t)MR * CC;            // 3M
    u16* wprojb = wqkvb  + (size_t)NQ * CC;            // 1M
    u16* Vc     = wprojb + (size_t)CC * CC;            // 4M  (B,T,C) V section
    u16* Qr     = Vc     + (size_t)MR * CC;            // 4M  (B,H,T,D)
    u16* Kr     = Qr     + (size_t)BB * HH * TT * DD;  // 4M
    u16* Vtg    = Kr     + (size_t)BB * HH * TT * DD;  // 4M  (B,H,D,T)
    u16* yb     = Vtg    + (size_t)BB * HH * TT * DD;  // 4M
    float2* tab = (float2*)(yb + (size_t)MR * CC);     // 2048*32 float2
    u32* ctr    = (u32*)(tab + (size_t)TT * 32);

    cvt_all<<<dim3(8448), 256, 0, stream>>>(x, Wqkv, Wproj, xb, wqkvb, wprojb, tab, ctr);

    gemm_qkv<<<dim3(24, 32), 256, 0, stream>>>(xb, wqkvb, bqkv, tab, Qr, Kr, Vc);

    vtrans<<<dim3(TT / 64, BB * HH), 64, 0, stream>>>(Vc, Vtg);

    attn_fwd<<<dim3(256), 512, 0, stream>>>(Qr, Kr, Vtg, yb, ctr);

    gemm_proj<<<dim3(8, 64), 256, 0, stream>>>(yb, wprojb, bproj, out);
}